// Round 15
// baseline (330.680 us; speedup 1.0000x reference)
//
#include <hip/hip_runtime.h>

typedef unsigned int u32;

// ---------------------------------------------------------------------------
// LiBNet forward, bit-packed ternary arithmetic + integer intermediates.
// dot over taps = popc(nzA & nzW) - 2*popc((sA ^ sW) & nzA & nzW)
// conv1: image staged in padded LDS (no xpad tensor), thread = 2x2 pooled
// window x 8 oc, straight-line fmaf chains. Pack->conv stages fused.
// ---------------------------------------------------------------------------

static __device__ __forceinline__ float fsign(float x) {
    return (x > 0.f) ? 1.f : ((x < 0.f) ? -1.f : 0.f);
}
static __device__ __forceinline__ u32 pack4(int a, int b, int c, int d) {
    return (a & 0xff) | ((b & 0xff) << 8) | ((c & 0xff) << 16) | ((u32)(d & 0xff) << 24);
}
// DPP on float (VALU pipe). 0xB1 = quad lane^1, 0x4E = quad lane^2,
// 0x124 = row_ror:4, 0x128 = row_ror:8 (16-lane row rotations).
template <int CTRL>
static __device__ __forceinline__ float dppf(float x) {
    int i = __builtin_amdgcn_mov_dpp(__float_as_int(x), CTRL, 0xF, 0xF, true);
    return __int_as_float(i);
}

// --- weight prep only (pad now done in-kernel by conv1f) ---
// conv1 weights TAP-MAJOR: swt[k*64+oc] = sign(w1[oc*48+k]).
__global__ __launch_bounds__(256) void k_wprep(const float* __restrict__ w1, float* __restrict__ swt,
                                               const float* __restrict__ w2_1, u32* __restrict__ wpk21,
                                               const float* __restrict__ w3_1, u32* __restrict__ wpk31,
                                               const float* __restrict__ w2_2, u32* __restrict__ wp22,
                                               const float* __restrict__ w3_2, u32* __restrict__ wp32)
{
    int blk = blockIdx.x, tid = threadIdx.x;
    if (blk < 12) {
        int i = blk * 256 + tid;
        if (i < 3072) {
            int k = i >> 6, oc = i & 63;
            swt[i] = fsign(w1[oc * 48 + k]);
        }
        return;
    }
    if (blk == 12) {
        if (tid < 64) {   // grouped 4x4 weights, C=64
            const float* p = w2_1 + tid * 32;
            for (int r = 0; r < 8; ++r) {
                u32 sn = 0, nz = 0;
                for (int kw = 0; kw < 4; ++kw) {
                    float v = p[r * 4 + kw];
                    sn |= (u32)(v > 0.f) << kw;
                    nz |= (u32)(v != 0.f) << kw;
                }
                wpk21[tid * 8 + r] = sn | (nz << 8);
            }
        }
        {                 // 1x1 weights 256x64
            const float* p = w2_2 + (size_t)tid * 64;
            for (int j = 0; j < 2; ++j) {
                u32 sv = 0, nv = 0;
                for (int k = 0; k < 32; ++k) {
                    float v = p[j * 32 + k];
                    sv |= (u32)(v > 0.f) << k;
                    nv |= (u32)(v != 0.f) << k;
                }
                wp22[tid * 4 + j] = sv;
                wp22[tid * 4 + 2 + j] = nv;
            }
        }
        return;
    }
    {                     // blk == 13
        {                 // grouped 4x4 weights, C=256
            const float* p = w3_1 + tid * 32;
            for (int r = 0; r < 8; ++r) {
                u32 sn = 0, nz = 0;
                for (int kw = 0; kw < 4; ++kw) {
                    float v = p[r * 4 + kw];
                    sn |= (u32)(v > 0.f) << kw;
                    nz |= (u32)(v != 0.f) << kw;
                }
                wpk31[tid * 8 + r] = sn | (nz << 8);
            }
        }
        {                 // 1x1 weights 256x256
            const float* p = w3_2 + (size_t)tid * 256;
            for (int j = 0; j < 8; ++j) {
                u32 sv = 0, nv = 0;
                for (int k = 0; k < 32; ++k) {
                    float v = p[j * 32 + k];
                    sv |= (u32)(v > 0.f) << k;
                    nv |= (u32)(v != 0.f) << k;
                }
                wp32[tid * 16 + j] = sv;
                wp32[tid * 16 + 8 + j] = nv;
            }
        }
    }
}

// --- conv1 fused: LDS-staged padded image; thread = 2x2 pool window x 8 oc ---
__global__ __launch_bounds__(256) void k_conv1f(const float* __restrict__ x,
                                                const float* __restrict__ swt,
                                                const float* __restrict__ g1,
                                                float* __restrict__ ppool,
                                                double* __restrict__ part)
{
    __shared__ float sx[3 * 1260];      // padded image [3][35 rows][36 cols]
    __shared__ float sacc_s[8 * 17];    // [j][16 s16-partials], pad 17
    __shared__ float sacc_q[8 * 17];
    int b = blockIdx.x >> 3, ocg = blockIdx.x & 7;
    int t = threadIdx.x;
    int lane = t & 63, wv = t >> 6;
    for (int i = t; i < 3780; i += 256) sx[i] = 0.f;
    __syncthreads();
    const float* xb = x + (size_t)b * 3072;
#pragma unroll
    for (int k = 0; k < 12; ++k) {
        int i = t + k * 256;
        int w = i & 31, h = (i >> 5) & 31, ic = i >> 10;
        sx[ic * 1260 + (h + 1) * 36 + (w + 1)] = xb[i];
    }
    __syncthreads();
    int oh = t >> 4, ow = t & 15;       // pooled position
    const float* xw = sx + (2 * oh) * 36 + 2 * ow;
    float acc0[8], acc1[8], acc2[8], acc3[8];   // [pos(r,c)][oc j]
#pragma unroll
    for (int j = 0; j < 8; ++j) { acc0[j] = 0.f; acc1[j] = 0.f; acc2[j] = 0.f; acc3[j] = 0.f; }
#pragma unroll
    for (int ic = 0; ic < 3; ++ic) {
        const float* xr = xw + ic * 1260;
        const float* wic = swt + ic * 1024 + ocg * 8;
#pragma unroll
        for (int rr = 0; rr < 5; ++rr) {
            float2 a01 = *(const float2*)xr;
            float2 a23 = *(const float2*)(xr + 2);
            float x0 = a01.x, x1 = a01.y, x2 = a23.x, x3 = a23.y, x4 = xr[4];
            if (rr <= 3) {              // contributes to out-row 2oh via kh=rr
                const float* wA = wic + rr * 256;
#pragma unroll
                for (int j = 0; j < 8; ++j) {
                    float w0 = wA[j], w1 = wA[64 + j], w2 = wA[128 + j], w3 = wA[192 + j];
                    acc0[j] = __builtin_fmaf(x0, w0, acc0[j]);
                    acc0[j] = __builtin_fmaf(x1, w1, acc0[j]);
                    acc0[j] = __builtin_fmaf(x2, w2, acc0[j]);
                    acc0[j] = __builtin_fmaf(x3, w3, acc0[j]);
                    acc1[j] = __builtin_fmaf(x1, w0, acc1[j]);
                    acc1[j] = __builtin_fmaf(x2, w1, acc1[j]);
                    acc1[j] = __builtin_fmaf(x3, w2, acc1[j]);
                    acc1[j] = __builtin_fmaf(x4, w3, acc1[j]);
                }
            }
            if (rr >= 1) {              // contributes to out-row 2oh+1 via kh=rr-1
                const float* wB = wic + (rr - 1) * 256;
#pragma unroll
                for (int j = 0; j < 8; ++j) {
                    float w0 = wB[j], w1 = wB[64 + j], w2 = wB[128 + j], w3 = wB[192 + j];
                    acc2[j] = __builtin_fmaf(x0, w0, acc2[j]);
                    acc2[j] = __builtin_fmaf(x1, w1, acc2[j]);
                    acc2[j] = __builtin_fmaf(x2, w2, acc2[j]);
                    acc2[j] = __builtin_fmaf(x3, w3, acc2[j]);
                    acc3[j] = __builtin_fmaf(x1, w0, acc3[j]);
                    acc3[j] = __builtin_fmaf(x2, w1, acc3[j]);
                    acc3[j] = __builtin_fmaf(x3, w2, acc3[j]);
                    acc3[j] = __builtin_fmaf(x4, w3, acc3[j]);
                }
            }
            xr += 36;
        }
    }
    bool owner16 = ((lane & 15) == 0);
    float* ppb = ppool + ((size_t)(b * 64 + ocg * 8)) * 256 + t;
#pragma unroll
    for (int j = 0; j < 8; ++j) {
        float a0 = acc0[j], a1 = acc1[j], a2 = acc2[j], a3 = acc3[j];
        bool posi = (g1[ocg * 8 + j] > 0.f);    // == sign(bn scale), uniform
        float pooled = posi ? fmaxf(fmaxf(a0, a1), fmaxf(a2, a3))
                            : fminf(fminf(a0, a1), fminf(a2, a3));
        float s = (a0 + a1) + (a2 + a3);
        float sq = a0 * a0 + a1 * a1 + a2 * a2 + a3 * a3;
        s += dppf<0xB1>(s);   sq += dppf<0xB1>(sq);
        s += dppf<0x4E>(s);   sq += dppf<0x4E>(sq);
        s += dppf<0x124>(s);  sq += dppf<0x124>(sq);
        s += dppf<0x128>(s);  sq += dppf<0x128>(sq);
        if (owner16) {
            int idx = j * 17 + wv * 4 + (lane >> 4);
            sacc_s[idx] = s;
            sacc_q[idx] = sq;
        }
        ppb[j * 256] = pooled;
    }
    __syncthreads();
    if (t < 16) {
        int j = t >> 1, half = t & 1;
        const float* sp = (half ? sacc_q : sacc_s) + j * 17;
        double acc = 0.0;
        for (int i = 0; i < 16; ++i) acc += (double)sp[i];
        part[(((size_t)(ocg * 8 + j)) * 512 + b) * 2 + half] = acc;
    }
}

// --- finalize: block per channel; mean/var -> power-of-two shift scale ---
__global__ __launch_bounds__(256) void k_finalize2(const double* __restrict__ part,
                                                   int nch, int N,
                                                   const float* __restrict__ gamma,
                                                   const float* __restrict__ beta,
                                                   float4* __restrict__ st)
{
    int c = blockIdx.x;
    double s = 0.0, sq = 0.0;
    for (int i = threadIdx.x; i < nch; i += 256) {
        s  += part[((size_t)c * nch + i) * 2];
        sq += part[((size_t)c * nch + i) * 2 + 1];
    }
    __shared__ double ss[256];
    __shared__ double sb[256];
    ss[threadIdx.x] = s; sb[threadIdx.x] = sq;
    __syncthreads();
    for (int stp = 128; stp > 0; stp >>= 1) {
        if (threadIdx.x < stp) {
            ss[threadIdx.x] += ss[threadIdx.x + stp];
            sb[threadIdx.x] += sb[threadIdx.x + stp];
        }
        __syncthreads();
    }
    if (threadIdx.x == 0) {
        double mean = ss[0] / (double)N;
        double var = sb[0] / (double)N - mean * mean;
        float inv = gamma[c] / sqrtf((float)var + 1e-5f);
        float sh = rintf(log2f(fabsf(inv) + 1e-12f));
        sh = fminf(fmaxf(sh, -4.f), 4.f);
        float scale = copysignf(exp2f(sh), inv);
        st[c] = make_float4((float)mean, scale, beta[c], 0.f);
    }
}

// --- merged stats+finalize, int8 tensor [512][256][256] per channel ---
__global__ __launch_bounds__(256) void k_statsfin8(const signed char* __restrict__ in,
                                                   const float* __restrict__ gamma,
                                                   const float* __restrict__ beta,
                                                   float4* __restrict__ st)
{
    int c = blockIdx.x;
    int s = 0, sq = 0;
    for (int i = threadIdx.x; i < 32768; i += 256) {   // 512 b x 64 words
        int b = i >> 6, w = i & 63;
        u32 v = ((const u32*)in)[((size_t)(b * 256 + c) << 6) + w];
        int x0 = (int)(v << 24) >> 24, x1 = (int)(v << 16) >> 24;
        int x2 = (int)(v << 8) >> 24,  x3 = (int)v >> 24;
        s += x0 + x1 + x2 + x3;
        sq += x0 * x0 + x1 * x1 + x2 * x2 + x3 * x3;
    }
    __shared__ int ss[256];
    __shared__ int sb[256];
    ss[threadIdx.x] = s; sb[threadIdx.x] = sq;
    __syncthreads();
    for (int stp = 128; stp > 0; stp >>= 1) {
        if (threadIdx.x < stp) {
            ss[threadIdx.x] += ss[threadIdx.x + stp];
            sb[threadIdx.x] += sb[threadIdx.x + stp];
        }
        __syncthreads();
    }
    if (threadIdx.x == 0) {
        double mean = (double)ss[0] / 131072.0;
        double var = (double)sb[0] / 131072.0 - mean * mean;
        float inv = gamma[c] / sqrtf((float)var + 1e-5f);
        float sh = rintf(log2f(fabsf(inv) + 1e-12f));
        sh = fminf(fmaxf(sh, -4.f), 4.f);
        float scale = copysignf(exp2f(sh), inv);
        st[c] = make_float4((float)mean, scale, beta[c], 0.f);
    }
}

// --- merged stats+finalize, int16 tensor [512][256][64] per channel ---
__global__ __launch_bounds__(256) void k_statsfin16(const short* __restrict__ in,
                                                    const float* __restrict__ gamma,
                                                    const float* __restrict__ beta,
                                                    float4* __restrict__ st)
{
    int c = blockIdx.x;
    int s = 0, sq = 0;
    for (int i = threadIdx.x; i < 16384; i += 256) {   // 512 b x 32 words
        int b = i >> 5, w = i & 31;
        u32 v = ((const u32*)in)[((size_t)(b * 256 + c) << 5) + w];
        int x0 = (int)(v << 16) >> 16, x1 = (int)v >> 16;
        s += x0 + x1;
        sq += x0 * x0 + x1 * x1;
    }
    __shared__ double ss[256];
    __shared__ double sb[256];
    ss[threadIdx.x] = (double)s; sb[threadIdx.x] = (double)sq;
    __syncthreads();
    for (int stp = 128; stp > 0; stp >>= 1) {
        if (threadIdx.x < stp) {
            ss[threadIdx.x] += ss[threadIdx.x + stp];
            sb[threadIdx.x] += sb[threadIdx.x + stp];
        }
        __syncthreads();
    }
    if (threadIdx.x == 0) {
        double mean = ss[0] / 32768.0;
        double var = sb[0] / 32768.0 - mean * mean;
        float inv = gamma[c] / sqrtf((float)var + 1e-5f);
        float sh = rintf(log2f(fabsf(inv) + 1e-12f));
        sh = fminf(fmaxf(sh, -4.f), 4.f);
        float scale = copysignf(exp2f(sh), inv);
        st[c] = make_float4((float)mean, scale, beta[c], 0.f);
    }
}

// --- FUSED layer-2 head: bnpick(ppool) -> LDS packed rows -> grouped conv ---
__global__ __launch_bounds__(512) void k_fuse2(const float* __restrict__ ppool,
                                               const float4* __restrict__ st,
                                               const u32* __restrict__ wpk,
                                               signed char* __restrict__ out,
                                               double* __restrict__ part)
{
    __shared__ u32 lspk[64 * 20];
    __shared__ u32 lnpk[64 * 20];
    int b = blockIdx.x, t = threadIdx.x;
#pragma unroll
    for (int k = 0; k < 2; ++k) {
        int e = t + k * 512;
        int c = e >> 4, oh = e & 15;
        float4 s = st[c];
        const float4* p = (const float4*)(ppool + ((size_t)(b * 64 + c)) * 256 + oh * 16);
        u32 sb = 0, nb = 0;
#pragma unroll
        for (int j = 0; j < 4; ++j) {
            float4 v4 = p[j];
            float vs[4] = {v4.x, v4.y, v4.z, v4.w};
#pragma unroll
            for (int kk = 0; kk < 4; ++kk) {
                float v = (vs[kk] - s.x) * s.y + s.z;
                int ow = j * 4 + kk;
                sb |= (u32)(v > 0.f) << (ow + 1);
                nb |= (u32)(v != 0.f) << (ow + 1);
            }
        }
        lspk[c * 20 + 1 + oh] = sb;
        lnpk[c * 20 + 1 + oh] = nb;
        if (oh < 4) {
            int zs = (oh == 0) ? 0 : (16 + oh);
            lspk[c * 20 + zs] = 0; lnpk[c * 20 + zs] = 0;
        }
    }
    __syncthreads();
    int g = t >> 4, h = t & 15;
    const u32* sp = lspk + (2 * g) * 20 + h;
    const u32* np = lnpk + (2 * g) * 20 + h;
    u32 S[8], N[8];
#pragma unroll
    for (int jc = 0; jc < 2; ++jc)
#pragma unroll
        for (int jj = 0; jj < 4; ++jj) {
            S[jc * 4 + jj] = sp[jc * 20 + jj];
            N[jc * 4 + jj] = np[jc * 20 + jj];
        }
    const u32* wq = wpk + (size_t)(2 * g) * 8;
    u32 Ws0[8], Wn0[8], Ws1[8], Wn1[8];
#pragma unroll
    for (int r = 0; r < 8; ++r) {
        u32 a = wq[r];      Ws0[r] = a & 15u;  Wn0[r] = (a >> 8) & 15u;
        u32 bb = wq[8 + r]; Ws1[r] = bb & 15u; Wn1[r] = (bb >> 8) & 15u;
    }
    int v0[16], v1[16];
    int s0 = 0, q0 = 0, s1 = 0, q1 = 0;
#pragma unroll
    for (int w = 0; w < 16; ++w) {
        int snz0 = 0, smis0 = 0, snz1 = 0, smis1 = 0;
#pragma unroll
        for (int r = 0; r < 8; ++r) {
            u32 ss = (S[r] >> w) & 15u;
            u32 nn = (N[r] >> w) & 15u;
            u32 nz0 = nn & Wn0[r]; u32 m0 = (ss ^ Ws0[r]) & nz0;
            snz0 += __popc(nz0); smis0 += __popc(m0);
            u32 nz1 = nn & Wn1[r]; u32 m1 = (ss ^ Ws1[r]) & nz1;
            snz1 += __popc(nz1); smis1 += __popc(m1);
        }
        v0[w] = snz0 - 2 * smis0;
        v1[w] = snz1 - 2 * smis1;
        s0 += v0[w]; q0 += v0[w] * v0[w];
        s1 += v1[w]; q1 += v1[w] * v1[w];
    }
#pragma unroll
    for (int m = 1; m < 16; m <<= 1) {
        s0 += __shfl_xor(s0, m); q0 += __shfl_xor(q0, m);
        s1 += __shfl_xor(s1, m); q1 += __shfl_xor(q1, m);
    }
    if (h == 0) {
        part[((size_t)(2 * g) * 512 + b) * 2]         = (double)s0;
        part[((size_t)(2 * g) * 512 + b) * 2 + 1]     = (double)q0;
        part[((size_t)(2 * g + 1) * 512 + b) * 2]     = (double)s1;
        part[((size_t)(2 * g + 1) * 512 + b) * 2 + 1] = (double)q1;
    }
    signed char* o0 = out + ((size_t)((b * 64 + 2 * g) * 16 + h)) * 16;
    signed char* o1 = o0 + 256;
    u32 wb0[4], wb1[4];
#pragma unroll
    for (int j = 0; j < 4; ++j) {
        wb0[j] = pack4(v0[4*j], v0[4*j+1], v0[4*j+2], v0[4*j+3]);
        wb1[j] = pack4(v1[4*j], v1[4*j+1], v1[4*j+2], v1[4*j+3]);
    }
    *(uint4*)o0 = make_uint4(wb0[0], wb0[1], wb0[2], wb0[3]);
    *(uint4*)o1 = make_uint4(wb1[0], wb1[1], wb1[2], wb1[3]);
}

// --- 1x1 conv Cin=64->Cout=256, HW=256, int8 out, FUSED bn2_1 binarize+pack ---
__global__ __launch_bounds__(256) void k_conv1x1_bp2(const signed char* __restrict__ q8,
                                                     const float4* __restrict__ st,
                                                     const u32* __restrict__ wp,
                                                     signed char* __restrict__ out)
{
    int t = blockIdx.x * 256 + threadIdx.x;   // t = b*256 + hw
    int hw = t & 255; int b = t >> 8;
    const signed char* qp = q8 + (size_t)b * 64 * 256 + hw;
    u32 as0 = 0, as1 = 0, an0 = 0, an1 = 0;
#pragma unroll
    for (int k = 0; k < 32; ++k) {
        float4 s = st[k];                       // uniform -> s_load
        float v = ((float)qp[k * 256] - s.x) * s.y + s.z;   // coalesced byte load
        as0 |= (u32)(v > 0.f) << k;
        an0 |= (u32)(v != 0.f) << k;
    }
#pragma unroll
    for (int k = 0; k < 32; ++k) {
        float4 s = st[32 + k];
        float v = ((float)qp[(32 + k) * 256] - s.x) * s.y + s.z;
        as1 |= (u32)(v > 0.f) << k;
        an1 |= (u32)(v != 0.f) << k;
    }
    signed char* op = out + (size_t)b * 256 * 256 + hw;
#pragma unroll 8
    for (int oc = 0; oc < 256; ++oc) {
        uint4 wv = ((const uint4*)wp)[oc];      // wave-uniform -> scalar loads
        u32 nz0 = an0 & wv.z, nz1 = an1 & wv.w;
        u32 m0 = (as0 ^ wv.x) & nz0, m1 = (as1 ^ wv.y) & nz1;
        int dot = __popc(nz0) + __popc(nz1) - 2 * (__popc(m0) + __popc(m1));
        op[(size_t)oc << 8] = (signed char)dot;
    }
}

// --- FUSED layer-3 head: pool+pack(c22) -> LDS rows -> grouped conv ---
__global__ __launch_bounds__(512) void k_fuse3(const signed char* __restrict__ c22,
                                               const float4* __restrict__ st,
                                               const u32* __restrict__ wpk,
                                               signed char* __restrict__ out,
                                               double* __restrict__ part)
{
    __shared__ u32 lspk[256 * 12];
    __shared__ u32 lnpk[256 * 12];
    int b = blockIdx.x, t = threadIdx.x;
#pragma unroll
    for (int k = 0; k < 4; ++k) {
        int e = t + k * 512;
        int c = e >> 3, oh = e & 7;
        float4 s = st[c];
        const uint4* p = (const uint4*)(c22 + ((size_t)(b * 256 + c)) * 256 + (size_t)(2 * oh) * 16);
        uint4 r0 = p[0], r1 = p[1];
        bool pos = (s.y > 0.f);
        u32 rows0[4] = {r0.x, r0.y, r0.z, r0.w};
        u32 rows1[4] = {r1.x, r1.y, r1.z, r1.w};
        u32 sb = 0, nb = 0;
#pragma unroll
        for (int j = 0; j < 4; ++j) {
            u32 a = rows0[j], bw = rows1[j];
#pragma unroll
            for (int kk = 0; kk < 2; ++kk) {
                int sh0 = 24 - 16 * kk, sh1 = 16 - 16 * kk;
                int a0 = (int)(a  << sh0) >> 24, a1 = (int)(a  << sh1) >> 24;
                int a2 = (int)(bw << sh0) >> 24, a3 = (int)(bw << sh1) >> 24;
                int raw = pos ? max(max(a0, a1), max(a2, a3))
                              : min(min(a0, a1), min(a2, a3));
                float v = ((float)raw - s.x) * s.y + s.z;
                int ow = j * 2 + kk;
                sb |= (u32)(v > 0.f) << (ow + 1);
                nb |= (u32)(v != 0.f) << (ow + 1);
            }
        }
        lspk[c * 12 + 1 + oh] = sb;
        lnpk[c * 12 + 1 + oh] = nb;
        if (oh < 4) {
            int zs = (oh == 0) ? 0 : (8 + oh);
            lspk[c * 12 + zs] = 0; lnpk[c * 12 + zs] = 0;
        }
    }
    __syncthreads();
#pragma unroll
    for (int k = 0; k < 2; ++k) {
        int e = t + k * 512;
        int g = e >> 3, h = e & 7;
        const u32* sp = lspk + (2 * g) * 12 + h;
        const u32* np = lnpk + (2 * g) * 12 + h;
        u32 S[8], N[8];
#pragma unroll
        for (int jc = 0; jc < 2; ++jc)
#pragma unroll
            for (int jj = 0; jj < 4; ++jj) {
                S[jc * 4 + jj] = sp[jc * 12 + jj];
                N[jc * 4 + jj] = np[jc * 12 + jj];
            }
        const u32* wq = wpk + (size_t)(2 * g) * 8;
        u32 Ws0[8], Wn0[8], Ws1[8], Wn1[8];
#pragma unroll
        for (int r = 0; r < 8; ++r) {
            u32 a = wq[r];      Ws0[r] = a & 15u;  Wn0[r] = (a >> 8) & 15u;
            u32 bb = wq[8 + r]; Ws1[r] = bb & 15u; Wn1[r] = (bb >> 8) & 15u;
        }
        int v0[8], v1[8];
        int s0 = 0, q0 = 0, s1 = 0, q1 = 0;
#pragma unroll
        for (int w = 0; w < 8; ++w) {
            int snz0 = 0, smis0 = 0, snz1 = 0, smis1 = 0;
#pragma unroll
            for (int r = 0; r < 8; ++r) {
                u32 ss = (S[r] >> w) & 15u;
                u32 nn = (N[r] >> w) & 15u;
                u32 nz0 = nn & Wn0[r]; u32 m0 = (ss ^ Ws0[r]) & nz0;
                snz0 += __popc(nz0); smis0 += __popc(m0);
                u32 nz1 = nn & Wn1[r]; u32 m1 = (ss ^ Ws1[r]) & nz1;
                snz1 += __popc(nz1); smis1 += __popc(m1);
            }
            v0[w] = snz0 - 2 * smis0;
            v1[w] = snz1 - 2 * smis1;
            s0 += v0[w]; q0 += v0[w] * v0[w];
            s1 += v1[w]; q1 += v1[w] * v1[w];
        }
#pragma unroll
        for (int m = 1; m < 8; m <<= 1) {
            s0 += __shfl_xor(s0, m); q0 += __shfl_xor(q0, m);
            s1 += __shfl_xor(s1, m); q1 += __shfl_xor(q1, m);
        }
        if (h == 0) {
            part[((size_t)(2 * g) * 512 + b) * 2]         = (double)s0;
            part[((size_t)(2 * g) * 512 + b) * 2 + 1]     = (double)q0;
            part[((size_t)(2 * g + 1) * 512 + b) * 2]     = (double)s1;
            part[((size_t)(2 * g + 1) * 512 + b) * 2 + 1] = (double)q1;
        }
        signed char* o0 = out + ((size_t)((b * 256 + 2 * g) * 8 + h)) * 8;
        signed char* o1 = o0 + 64;
        *(uint2*)o0 = make_uint2(pack4(v0[0], v0[1], v0[2], v0[3]),
                                 pack4(v0[4], v0[5], v0[6], v0[7]));
        *(uint2*)o1 = make_uint2(pack4(v1[0], v1[1], v1[2], v1[3]),
                                 pack4(v1[4], v1[5], v1[6], v1[7]));
    }
}

// --- FUSED: bn+binarize+channel-pack (LDS) -> 1x1 conv Cin=256, int16 out ---
__global__ __launch_bounds__(256) void k_fuse4(const signed char* __restrict__ q8,
                                               const float4* __restrict__ st,
                                               const u32* __restrict__ wp,
                                               short* __restrict__ out)
{
    __shared__ u32 sq[4096];       // one image: 256ch x 64hw bytes
    __shared__ u32 act[64 * 17];   // [hw][16 words], pad 17
    int b = blockIdx.x, t = threadIdx.x;
    const u32* qb = (const u32*)(q8 + (size_t)b * 16384);
    for (int i = t; i < 4096; i += 256) sq[i] = qb[i];
    __syncthreads();
    {
        const signed char* s8p = (const signed char*)sq;
        int hw = t & 63, qd = t >> 6;
        u32 sv0 = 0, nv0 = 0, sv1 = 0, nv1 = 0;
#pragma unroll
        for (int k = 0; k < 32; ++k) {
            int c = qd * 64 + k;
            float4 s = st[c];
            float v = ((float)s8p[c * 64 + hw] - s.x) * s.y + s.z;
            sv0 |= (u32)(v > 0.f) << k;
            nv0 |= (u32)(v != 0.f) << k;
        }
#pragma unroll
        for (int k = 0; k < 32; ++k) {
            int c = qd * 64 + 32 + k;
            float4 s = st[c];
            float v = ((float)s8p[c * 64 + hw] - s.x) * s.y + s.z;
            sv1 |= (u32)(v > 0.f) << k;
            nv1 |= (u32)(v != 0.f) << k;
        }
        u32* ap = act + hw * 17;
        ap[qd * 2]     = sv0;
        ap[qd * 2 + 1] = sv1;
        ap[8 + qd * 2]     = nv0;
        ap[8 + qd * 2 + 1] = nv1;
    }
    __syncthreads();
    int hw = t & 63, ch = t >> 6;
    const u32* ap = act + hw * 17;
    u32 as[8], an[8];
#pragma unroll
    for (int j = 0; j < 8; ++j) { as[j] = ap[j]; an[j] = ap[8 + j]; }
    short* op = out + (size_t)b * 256 * 64 + hw;
#pragma unroll 4
    for (int oc = ch * 64; oc < ch * 64 + 64; ++oc) {
        const u32* wq = wp + oc * 16;
        int snz = 0, smis = 0;
#pragma unroll
        for (int j = 0; j < 8; ++j) {
            u32 nz = an[j] & wq[8 + j];
            u32 m = (as[j] ^ wq[j]) & nz;
            snz += __popc(nz); smis += __popc(m);
        }
        op[(size_t)oc * 64] = (short)(snz - 2 * smis);
    }
}

// --- FC: block per image, bn3_2 applied inline, features read once ---
__global__ __launch_bounds__(256) void k_fc2(const short* __restrict__ f,
                                             const float4* __restrict__ st,
                                             const float* __restrict__ fcw,
                                             const float* __restrict__ fcb,
                                             float* __restrict__ out)
{
    int b = blockIdx.x, t = threadIdx.x;
    int lane = t & 63, wv = t >> 6;
    const u32* fp = (const u32*)(f + (size_t)b * 16384);
    float acc[10];
#pragma unroll
    for (int n = 0; n < 10; ++n) acc[n] = 0.f;
    for (int i = 0; i < 32; ++i) {
        int j = i * 256 + t;                 // u32 index; features 2j, 2j+1
        u32 v = fp[j];
        float4 s = st[j >> 5];               // channel = (2j)>>6 = j>>5
        float f0 = ((float)((int)(v << 16) >> 16) - s.x) * s.y + s.z;
        float f1 = ((float)((int)v >> 16) - s.x) * s.y + s.z;
#pragma unroll
        for (int n = 0; n < 10; ++n) {
            float2 wv2 = *(const float2*)(fcw + (size_t)n * 16384 + 2 * j);
            acc[n] += f0 * wv2.x + f1 * wv2.y;
        }
    }
#pragma unroll
    for (int n = 0; n < 10; ++n)
#pragma unroll
        for (int m = 1; m < 64; m <<= 1) acc[n] += __shfl_xor(acc[n], m);
    __shared__ float sred[4][10];
    if (lane == 0)
#pragma unroll
        for (int n = 0; n < 10; ++n) sred[wv][n] = acc[n];
    __syncthreads();
    if (t < 10)
        out[b * 10 + t] = sred[0][t] + sred[1][t] + sred[2][t] + sred[3][t] + fcb[t];
}

extern "C" void kernel_launch(void* const* d_in, const int* in_sizes, int n_in,
                              void* d_out, int out_size, void* d_ws, size_t ws_size,
                              hipStream_t stream)
{
    const float* x    = (const float*)d_in[0];
    const float* w1   = (const float*)d_in[1];
    const float* g1   = (const float*)d_in[2];
    const float* b1   = (const float*)d_in[3];
    const float* w2_1 = (const float*)d_in[4];
    const float* g2_1 = (const float*)d_in[5];
    const float* b2_1 = (const float*)d_in[6];
    const float* w2_2 = (const float*)d_in[7];
    const float* g2_2 = (const float*)d_in[8];
    const float* b2_2 = (const float*)d_in[9];
    const float* w3_1 = (const float*)d_in[10];
    const float* g3_1 = (const float*)d_in[11];
    const float* b3_1 = (const float*)d_in[12];
    const float* w3_2 = (const float*)d_in[13];
    const float* g3_2 = (const float*)d_in[14];
    const float* b3_2 = (const float*)d_in[15];
    const float* fcw  = (const float*)d_in[16];
    const float* fcb  = (const float*)d_in[17];
    float* out = (float*)d_out;

    // workspace layout (bytes). ppool aliases later c22 (write-after-consume
    // ordering per launch sequence).
    const size_t OFF_PPOOL= 0;          // 33,554,432  (-> c22 later)
    const size_t OFF_F3   = 33554432;   // 16,777,216  conv3_2 int16 out
    const size_t OFF_Q    = 50331648;   //  8,388,608  convg int8 outs
    const size_t OFF_WPK21= 67108864;   //  2,048
    const size_t OFF_WPK31= 67110912;   //  8,192
    const size_t OFF_WP22 = 67119104;   //  4,096
    const size_t OFF_WP32 = 67123200;   //  16,384
    const size_t OFF_PART = 67139584;   //  2,097,152
    const size_t OFF_ST   = 69236736;   //  20,480     5 x 256 float4
    const size_t OFF_SWT  = 69257216;   //  12,288     conv1 signed weights, tap-major f32
    const size_t NEED     = OFF_SWT + 12288;
    if (ws_size < NEED) return;

    char* ws = (char*)d_ws;
    float* ppool = (float*)(ws + OFF_PPOOL);
    signed char* c22 = (signed char*)(ws + OFF_PPOOL); // after k_fuse2 consumes ppool
    short* f3  = (short*)(ws + OFF_F3);
    signed char* q8 = (signed char*)(ws + OFF_Q);
    u32* wpk21 = (u32*)(ws + OFF_WPK21);
    u32* wpk31 = (u32*)(ws + OFF_WPK31);
    u32* wp22  = (u32*)(ws + OFF_WP22);
    u32* wp32  = (u32*)(ws + OFF_WP32);
    double* part = (double*)(ws + OFF_PART);
    float4* st1  = (float4*)(ws + OFF_ST);
    float4* st21 = st1 + 256;
    float4* st22 = st21 + 256;
    float4* st31 = st22 + 256;
    float4* st32 = st31 + 256;
    float* swt   = (float*)(ws + OFF_SWT);

    // ---- weight prep (weights only; conv1f self-stages padded input) ----
    k_wprep<<<14, 256, 0, stream>>>(w1, swt, w2_1, wpk21, w3_1, wpk31,
                                    w2_2, wp22, w3_2, wp32);

    // ---- layer 1 ----
    k_conv1f<<<4096, 256, 0, stream>>>(x, swt, g1, ppool, part);
    k_finalize2<<<64, 256, 0, stream>>>(part, 512, 512 * 1024, g1, b1, st1);

    // ---- layer 2 (pack+gconv fused) ----
    k_fuse2<<<512, 512, 0, stream>>>(ppool, st1, wpk21, q8, part);
    k_finalize2<<<64, 256, 0, stream>>>(part, 512, 512 * 256, g2_1, b2_1, st21);
    k_conv1x1_bp2<<<512, 256, 0, stream>>>(q8, st21, wp22, c22);
    k_statsfin8<<<256, 256, 0, stream>>>(c22, g2_2, b2_2, st22);

    // ---- layer 3 (pool+pack+gconv fused; pack+1x1 fused) ----
    k_fuse3<<<512, 512, 0, stream>>>(c22, st22, wpk31, q8, part);
    k_finalize2<<<256, 256, 0, stream>>>(part, 512, 512 * 64, g3_1, b3_1, st31);
    k_fuse4<<<512, 256, 0, stream>>>(q8, st31, wp32, f3);
    k_statsfin16<<<256, 256, 0, stream>>>(f3, g3_2, b3_2, st32);

    // ---- FC (bn3_2 inline) ----
    k_fc2<<<512, 256, 0, stream>>>(f3, st32, fcw, fcb, out);
}

// Round 16
// 241.727 us; speedup vs baseline: 1.3680x; 1.3680x over previous
//
#include <hip/hip_runtime.h>

typedef unsigned int u32;

// ---------------------------------------------------------------------------
// LiBNet forward, bit-packed ternary arithmetic + integer intermediates.
// dot over taps = popc(nzA & nzW) - 2*popc((sA ^ sW) & nzA & nzW)
// conv1: thread = 2x2 pooled window x 8 oc, fmaf chains, float2 row loads
// (xpad rows padded to 36 floats for 8B alignment; global/L2-resident — LDS
// staging measured WORSE: bank conflicts + ds_read rematerialization).
// Pack->conv stages fused per image; stats+finalize merged where standalone.
// ---------------------------------------------------------------------------

static __device__ __forceinline__ float fsign(float x) {
    return (x > 0.f) ? 1.f : ((x < 0.f) ? -1.f : 0.f);
}
static __device__ __forceinline__ u32 pack4(int a, int b, int c, int d) {
    return (a & 0xff) | ((b & 0xff) << 8) | ((c & 0xff) << 16) | ((u32)(d & 0xff) << 24);
}
// DPP on float (VALU pipe). 0xB1 = quad lane^1, 0x4E = quad lane^2,
// 0x124 = row_ror:4, 0x128 = row_ror:8 (16-lane row rotations).
template <int CTRL>
static __device__ __forceinline__ float dppf(float x) {
    int i = __builtin_amdgcn_mov_dpp(__float_as_int(x), CTRL, 0xF, 0xF, true);
    return __int_as_float(i);
}

// --- weight prep + input padding (one launch) ---
// conv1 weights TAP-MAJOR: swt[k*64+oc] = sign(w1[oc*48+k]).
// xpad layout: [512*3][35 rows][36 cols] (col 35 = align pad, zeroed).
__global__ __launch_bounds__(256) void k_wprep(const float* __restrict__ w1, float* __restrict__ swt,
                                               const float* __restrict__ w2_1, u32* __restrict__ wpk21,
                                               const float* __restrict__ w3_1, u32* __restrict__ wpk31,
                                               const float* __restrict__ w2_2, u32* __restrict__ wp22,
                                               const float* __restrict__ w3_2, u32* __restrict__ wp32,
                                               const float* __restrict__ x, float* __restrict__ xpad)
{
    int blk = blockIdx.x, tid = threadIdx.x;
    if (blk >= 14) {                    // pad x -> xpad
        int i = (blk - 14) * 256 + tid;
        if (i < 1935360) {
            int bic = i / 1260;
            int rem = i - bic * 1260;
            int r = rem / 36, c = rem - r * 36;
            float v = 0.f;
            if (r >= 1 && r <= 32 && c >= 1 && c <= 32)
                v = x[bic * 1024 + (r - 1) * 32 + (c - 1)];
            xpad[i] = v;
        }
        return;
    }
    if (blk < 12) {
        int i = blk * 256 + tid;
        if (i < 3072) {
            int k = i >> 6, oc = i & 63;
            swt[i] = fsign(w1[oc * 48 + k]);
        }
        return;
    }
    if (blk == 12) {
        if (tid < 64) {   // grouped 4x4 weights, C=64
            const float* p = w2_1 + tid * 32;
            for (int r = 0; r < 8; ++r) {
                u32 sn = 0, nz = 0;
                for (int kw = 0; kw < 4; ++kw) {
                    float v = p[r * 4 + kw];
                    sn |= (u32)(v > 0.f) << kw;
                    nz |= (u32)(v != 0.f) << kw;
                }
                wpk21[tid * 8 + r] = sn | (nz << 8);
            }
        }
        {                 // 1x1 weights 256x64
            const float* p = w2_2 + (size_t)tid * 64;
            for (int j = 0; j < 2; ++j) {
                u32 sv = 0, nv = 0;
                for (int k = 0; k < 32; ++k) {
                    float v = p[j * 32 + k];
                    sv |= (u32)(v > 0.f) << k;
                    nv |= (u32)(v != 0.f) << k;
                }
                wp22[tid * 4 + j] = sv;
                wp22[tid * 4 + 2 + j] = nv;
            }
        }
        return;
    }
    {                     // blk == 13
        {                 // grouped 4x4 weights, C=256
            const float* p = w3_1 + tid * 32;
            for (int r = 0; r < 8; ++r) {
                u32 sn = 0, nz = 0;
                for (int kw = 0; kw < 4; ++kw) {
                    float v = p[r * 4 + kw];
                    sn |= (u32)(v > 0.f) << kw;
                    nz |= (u32)(v != 0.f) << kw;
                }
                wpk31[tid * 8 + r] = sn | (nz << 8);
            }
        }
        {                 // 1x1 weights 256x256
            const float* p = w3_2 + (size_t)tid * 256;
            for (int j = 0; j < 8; ++j) {
                u32 sv = 0, nv = 0;
                for (int k = 0; k < 32; ++k) {
                    float v = p[j * 32 + k];
                    sv |= (u32)(v > 0.f) << k;
                    nv |= (u32)(v != 0.f) << k;
                }
                wp32[tid * 16 + j] = sv;
                wp32[tid * 16 + 8 + j] = nv;
            }
        }
    }
}

// --- conv1 fused: block = (image, oc-group of 8); thread = 2x2 pool window ---
__global__ __launch_bounds__(256) void k_conv1f(const float* __restrict__ xpad,
                                                const float* __restrict__ swt,
                                                const float* __restrict__ g1,
                                                float* __restrict__ ppool,
                                                double* __restrict__ part)
{
    __shared__ float sacc_s[8 * 17];    // [j][16 s16-partials], pad 17
    __shared__ float sacc_q[8 * 17];
    int b = blockIdx.x >> 3, ocg = blockIdx.x & 7;
    int t = threadIdx.x;
    int lane = t & 63, wv = t >> 6;
    int oh = t >> 4, ow = t & 15;       // pooled position
    const float* xb = xpad + (size_t)b * 3780 + (2 * oh) * 36 + 2 * ow;
    float acc0[8], acc1[8], acc2[8], acc3[8];   // [pos(r,c)][oc j]
#pragma unroll
    for (int j = 0; j < 8; ++j) { acc0[j] = 0.f; acc1[j] = 0.f; acc2[j] = 0.f; acc3[j] = 0.f; }
#pragma unroll 1
    for (int ic = 0; ic < 3; ++ic) {
        const float* xr = xb + ic * 1260;
        const float* wic = swt + ic * 1024 + ocg * 8;
#pragma unroll 1
        for (int rr = 0; rr < 5; ++rr) {
            float2 a01 = *(const float2*)xr;
            float2 a23 = *(const float2*)(xr + 2);
            float x0 = a01.x, x1 = a01.y, x2 = a23.x, x3 = a23.y, x4 = xr[4];
            if (rr <= 3) {              // contributes to out-row 2oh via kh=rr
                const float* wA = wic + rr * 256;
#pragma unroll
                for (int j = 0; j < 8; ++j) {
                    float w0 = wA[j], w1 = wA[64 + j], w2 = wA[128 + j], w3 = wA[192 + j];
                    acc0[j] = __builtin_fmaf(x0, w0, acc0[j]);
                    acc0[j] = __builtin_fmaf(x1, w1, acc0[j]);
                    acc0[j] = __builtin_fmaf(x2, w2, acc0[j]);
                    acc0[j] = __builtin_fmaf(x3, w3, acc0[j]);
                    acc1[j] = __builtin_fmaf(x1, w0, acc1[j]);
                    acc1[j] = __builtin_fmaf(x2, w1, acc1[j]);
                    acc1[j] = __builtin_fmaf(x3, w2, acc1[j]);
                    acc1[j] = __builtin_fmaf(x4, w3, acc1[j]);
                }
            }
            if (rr >= 1) {              // contributes to out-row 2oh+1 via kh=rr-1
                const float* wB = wic + (rr - 1) * 256;
#pragma unroll
                for (int j = 0; j < 8; ++j) {
                    float w0 = wB[j], w1 = wB[64 + j], w2 = wB[128 + j], w3 = wB[192 + j];
                    acc2[j] = __builtin_fmaf(x0, w0, acc2[j]);
                    acc2[j] = __builtin_fmaf(x1, w1, acc2[j]);
                    acc2[j] = __builtin_fmaf(x2, w2, acc2[j]);
                    acc2[j] = __builtin_fmaf(x3, w3, acc2[j]);
                    acc3[j] = __builtin_fmaf(x1, w0, acc3[j]);
                    acc3[j] = __builtin_fmaf(x2, w1, acc3[j]);
                    acc3[j] = __builtin_fmaf(x3, w2, acc3[j]);
                    acc3[j] = __builtin_fmaf(x4, w3, acc3[j]);
                }
            }
            xr += 36;
        }
    }
    bool owner16 = ((lane & 15) == 0);
    float* ppb = ppool + ((size_t)(b * 64 + ocg * 8)) * 256 + t;
#pragma unroll
    for (int j = 0; j < 8; ++j) {
        float a0 = acc0[j], a1 = acc1[j], a2 = acc2[j], a3 = acc3[j];
        bool posi = (g1[ocg * 8 + j] > 0.f);    // == sign(bn scale), uniform
        float pooled = posi ? fmaxf(fmaxf(a0, a1), fmaxf(a2, a3))
                            : fminf(fminf(a0, a1), fminf(a2, a3));
        float s = (a0 + a1) + (a2 + a3);
        float sq = a0 * a0 + a1 * a1 + a2 * a2 + a3 * a3;
        s += dppf<0xB1>(s);   sq += dppf<0xB1>(sq);
        s += dppf<0x4E>(s);   sq += dppf<0x4E>(sq);
        s += dppf<0x124>(s);  sq += dppf<0x124>(sq);
        s += dppf<0x128>(s);  sq += dppf<0x128>(sq);
        if (owner16) {
            int idx = j * 17 + wv * 4 + (lane >> 4);
            sacc_s[idx] = s;
            sacc_q[idx] = sq;
        }
        ppb[j * 256] = pooled;
    }
    __syncthreads();
    if (t < 16) {
        int j = t >> 1, half = t & 1;
        const float* sp = (half ? sacc_q : sacc_s) + j * 17;
        double acc = 0.0;
        for (int i = 0; i < 16; ++i) acc += (double)sp[i];
        part[(((size_t)(ocg * 8 + j)) * 512 + b) * 2 + half] = acc;
    }
}

// --- finalize: block per channel; mean/var -> power-of-two shift scale ---
__global__ __launch_bounds__(256) void k_finalize2(const double* __restrict__ part,
                                                   int nch, int N,
                                                   const float* __restrict__ gamma,
                                                   const float* __restrict__ beta,
                                                   float4* __restrict__ st)
{
    int c = blockIdx.x;
    double s = 0.0, sq = 0.0;
    for (int i = threadIdx.x; i < nch; i += 256) {
        s  += part[((size_t)c * nch + i) * 2];
        sq += part[((size_t)c * nch + i) * 2 + 1];
    }
    __shared__ double ss[256];
    __shared__ double sb[256];
    ss[threadIdx.x] = s; sb[threadIdx.x] = sq;
    __syncthreads();
    for (int stp = 128; stp > 0; stp >>= 1) {
        if (threadIdx.x < stp) {
            ss[threadIdx.x] += ss[threadIdx.x + stp];
            sb[threadIdx.x] += sb[threadIdx.x + stp];
        }
        __syncthreads();
    }
    if (threadIdx.x == 0) {
        double mean = ss[0] / (double)N;
        double var = sb[0] / (double)N - mean * mean;
        float inv = gamma[c] / sqrtf((float)var + 1e-5f);
        float sh = rintf(log2f(fabsf(inv) + 1e-12f));
        sh = fminf(fmaxf(sh, -4.f), 4.f);
        float scale = copysignf(exp2f(sh), inv);
        st[c] = make_float4((float)mean, scale, beta[c], 0.f);
    }
}

// --- merged stats+finalize, int8 tensor [512][256][256] per channel ---
__global__ __launch_bounds__(256) void k_statsfin8(const signed char* __restrict__ in,
                                                   const float* __restrict__ gamma,
                                                   const float* __restrict__ beta,
                                                   float4* __restrict__ st)
{
    int c = blockIdx.x;
    int s = 0, sq = 0;
    for (int i = threadIdx.x; i < 32768; i += 256) {   // 512 b x 64 words
        int b = i >> 6, w = i & 63;
        u32 v = ((const u32*)in)[((size_t)(b * 256 + c) << 6) + w];
        int x0 = (int)(v << 24) >> 24, x1 = (int)(v << 16) >> 24;
        int x2 = (int)(v << 8) >> 24,  x3 = (int)v >> 24;
        s += x0 + x1 + x2 + x3;
        sq += x0 * x0 + x1 * x1 + x2 * x2 + x3 * x3;
    }
    __shared__ int ss[256];
    __shared__ int sb[256];
    ss[threadIdx.x] = s; sb[threadIdx.x] = sq;
    __syncthreads();
    for (int stp = 128; stp > 0; stp >>= 1) {
        if (threadIdx.x < stp) {
            ss[threadIdx.x] += ss[threadIdx.x + stp];
            sb[threadIdx.x] += sb[threadIdx.x + stp];
        }
        __syncthreads();
    }
    if (threadIdx.x == 0) {
        double mean = (double)ss[0] / 131072.0;
        double var = (double)sb[0] / 131072.0 - mean * mean;
        float inv = gamma[c] / sqrtf((float)var + 1e-5f);
        float sh = rintf(log2f(fabsf(inv) + 1e-12f));
        sh = fminf(fmaxf(sh, -4.f), 4.f);
        float scale = copysignf(exp2f(sh), inv);
        st[c] = make_float4((float)mean, scale, beta[c], 0.f);
    }
}

// --- merged stats+finalize, int16 tensor [512][256][64] per channel ---
__global__ __launch_bounds__(256) void k_statsfin16(const short* __restrict__ in,
                                                    const float* __restrict__ gamma,
                                                    const float* __restrict__ beta,
                                                    float4* __restrict__ st)
{
    int c = blockIdx.x;
    int s = 0, sq = 0;
    for (int i = threadIdx.x; i < 16384; i += 256) {   // 512 b x 32 words
        int b = i >> 5, w = i & 31;
        u32 v = ((const u32*)in)[((size_t)(b * 256 + c) << 5) + w];
        int x0 = (int)(v << 16) >> 16, x1 = (int)v >> 16;
        s += x0 + x1;
        sq += x0 * x0 + x1 * x1;
    }
    __shared__ double ss[256];
    __shared__ double sb[256];
    ss[threadIdx.x] = (double)s; sb[threadIdx.x] = (double)sq;
    __syncthreads();
    for (int stp = 128; stp > 0; stp >>= 1) {
        if (threadIdx.x < stp) {
            ss[threadIdx.x] += ss[threadIdx.x + stp];
            sb[threadIdx.x] += sb[threadIdx.x + stp];
        }
        __syncthreads();
    }
    if (threadIdx.x == 0) {
        double mean = ss[0] / 32768.0;
        double var = sb[0] / 32768.0 - mean * mean;
        float inv = gamma[c] / sqrtf((float)var + 1e-5f);
        float sh = rintf(log2f(fabsf(inv) + 1e-12f));
        sh = fminf(fmaxf(sh, -4.f), 4.f);
        float scale = copysignf(exp2f(sh), inv);
        st[c] = make_float4((float)mean, scale, beta[c], 0.f);
    }
}

// --- FUSED layer-2 head: bnpick(ppool) -> LDS packed rows -> grouped conv ---
__global__ __launch_bounds__(512) void k_fuse2(const float* __restrict__ ppool,
                                               const float4* __restrict__ st,
                                               const u32* __restrict__ wpk,
                                               signed char* __restrict__ out,
                                               double* __restrict__ part)
{
    __shared__ u32 lspk[64 * 20];
    __shared__ u32 lnpk[64 * 20];
    int b = blockIdx.x, t = threadIdx.x;
#pragma unroll
    for (int k = 0; k < 2; ++k) {
        int e = t + k * 512;
        int c = e >> 4, oh = e & 15;
        float4 s = st[c];
        const float4* p = (const float4*)(ppool + ((size_t)(b * 64 + c)) * 256 + oh * 16);
        u32 sb = 0, nb = 0;
#pragma unroll
        for (int j = 0; j < 4; ++j) {
            float4 v4 = p[j];
            float vs[4] = {v4.x, v4.y, v4.z, v4.w};
#pragma unroll
            for (int kk = 0; kk < 4; ++kk) {
                float v = (vs[kk] - s.x) * s.y + s.z;
                int ow = j * 4 + kk;
                sb |= (u32)(v > 0.f) << (ow + 1);
                nb |= (u32)(v != 0.f) << (ow + 1);
            }
        }
        lspk[c * 20 + 1 + oh] = sb;
        lnpk[c * 20 + 1 + oh] = nb;
        if (oh < 4) {
            int zs = (oh == 0) ? 0 : (16 + oh);
            lspk[c * 20 + zs] = 0; lnpk[c * 20 + zs] = 0;
        }
    }
    __syncthreads();
    int g = t >> 4, h = t & 15;
    const u32* sp = lspk + (2 * g) * 20 + h;
    const u32* np = lnpk + (2 * g) * 20 + h;
    u32 S[8], N[8];
#pragma unroll
    for (int jc = 0; jc < 2; ++jc)
#pragma unroll
        for (int jj = 0; jj < 4; ++jj) {
            S[jc * 4 + jj] = sp[jc * 20 + jj];
            N[jc * 4 + jj] = np[jc * 20 + jj];
        }
    const u32* wq = wpk + (size_t)(2 * g) * 8;
    u32 Ws0[8], Wn0[8], Ws1[8], Wn1[8];
#pragma unroll
    for (int r = 0; r < 8; ++r) {
        u32 a = wq[r];      Ws0[r] = a & 15u;  Wn0[r] = (a >> 8) & 15u;
        u32 bb = wq[8 + r]; Ws1[r] = bb & 15u; Wn1[r] = (bb >> 8) & 15u;
    }
    int v0[16], v1[16];
    int s0 = 0, q0 = 0, s1 = 0, q1 = 0;
#pragma unroll
    for (int w = 0; w < 16; ++w) {
        int snz0 = 0, smis0 = 0, snz1 = 0, smis1 = 0;
#pragma unroll
        for (int r = 0; r < 8; ++r) {
            u32 ss = (S[r] >> w) & 15u;
            u32 nn = (N[r] >> w) & 15u;
            u32 nz0 = nn & Wn0[r]; u32 m0 = (ss ^ Ws0[r]) & nz0;
            snz0 += __popc(nz0); smis0 += __popc(m0);
            u32 nz1 = nn & Wn1[r]; u32 m1 = (ss ^ Ws1[r]) & nz1;
            snz1 += __popc(nz1); smis1 += __popc(m1);
        }
        v0[w] = snz0 - 2 * smis0;
        v1[w] = snz1 - 2 * smis1;
        s0 += v0[w]; q0 += v0[w] * v0[w];
        s1 += v1[w]; q1 += v1[w] * v1[w];
    }
#pragma unroll
    for (int m = 1; m < 16; m <<= 1) {
        s0 += __shfl_xor(s0, m); q0 += __shfl_xor(q0, m);
        s1 += __shfl_xor(s1, m); q1 += __shfl_xor(q1, m);
    }
    if (h == 0) {
        part[((size_t)(2 * g) * 512 + b) * 2]         = (double)s0;
        part[((size_t)(2 * g) * 512 + b) * 2 + 1]     = (double)q0;
        part[((size_t)(2 * g + 1) * 512 + b) * 2]     = (double)s1;
        part[((size_t)(2 * g + 1) * 512 + b) * 2 + 1] = (double)q1;
    }
    signed char* o0 = out + ((size_t)((b * 64 + 2 * g) * 16 + h)) * 16;
    signed char* o1 = o0 + 256;
    u32 wb0[4], wb1[4];
#pragma unroll
    for (int j = 0; j < 4; ++j) {
        wb0[j] = pack4(v0[4*j], v0[4*j+1], v0[4*j+2], v0[4*j+3]);
        wb1[j] = pack4(v1[4*j], v1[4*j+1], v1[4*j+2], v1[4*j+3]);
    }
    *(uint4*)o0 = make_uint4(wb0[0], wb0[1], wb0[2], wb0[3]);
    *(uint4*)o1 = make_uint4(wb1[0], wb1[1], wb1[2], wb1[3]);
}

// --- 1x1 conv Cin=64->Cout=256, HW=256, int8 out, FUSED bn2_1 binarize+pack ---
__global__ __launch_bounds__(256) void k_conv1x1_bp2(const signed char* __restrict__ q8,
                                                     const float4* __restrict__ st,
                                                     const u32* __restrict__ wp,
                                                     signed char* __restrict__ out)
{
    int t = blockIdx.x * 256 + threadIdx.x;   // t = b*256 + hw
    int hw = t & 255; int b = t >> 8;
    const signed char* qp = q8 + (size_t)b * 64 * 256 + hw;
    u32 as0 = 0, as1 = 0, an0 = 0, an1 = 0;
#pragma unroll
    for (int k = 0; k < 32; ++k) {
        float4 s = st[k];                       // uniform -> s_load
        float v = ((float)qp[k * 256] - s.x) * s.y + s.z;   // coalesced byte load
        as0 |= (u32)(v > 0.f) << k;
        an0 |= (u32)(v != 0.f) << k;
    }
#pragma unroll
    for (int k = 0; k < 32; ++k) {
        float4 s = st[32 + k];
        float v = ((float)qp[(32 + k) * 256] - s.x) * s.y + s.z;
        as1 |= (u32)(v > 0.f) << k;
        an1 |= (u32)(v != 0.f) << k;
    }
    signed char* op = out + (size_t)b * 256 * 256 + hw;
#pragma unroll 8
    for (int oc = 0; oc < 256; ++oc) {
        uint4 wv = ((const uint4*)wp)[oc];      // wave-uniform -> scalar loads
        u32 nz0 = an0 & wv.z, nz1 = an1 & wv.w;
        u32 m0 = (as0 ^ wv.x) & nz0, m1 = (as1 ^ wv.y) & nz1;
        int dot = __popc(nz0) + __popc(nz1) - 2 * (__popc(m0) + __popc(m1));
        op[(size_t)oc << 8] = (signed char)dot;
    }
}

// --- FUSED layer-3 head: pool+pack(c22) -> LDS rows -> grouped conv ---
__global__ __launch_bounds__(512) void k_fuse3(const signed char* __restrict__ c22,
                                               const float4* __restrict__ st,
                                               const u32* __restrict__ wpk,
                                               signed char* __restrict__ out,
                                               double* __restrict__ part)
{
    __shared__ u32 lspk[256 * 12];
    __shared__ u32 lnpk[256 * 12];
    int b = blockIdx.x, t = threadIdx.x;
#pragma unroll
    for (int k = 0; k < 4; ++k) {
        int e = t + k * 512;
        int c = e >> 3, oh = e & 7;
        float4 s = st[c];
        const uint4* p = (const uint4*)(c22 + ((size_t)(b * 256 + c)) * 256 + (size_t)(2 * oh) * 16);
        uint4 r0 = p[0], r1 = p[1];
        bool pos = (s.y > 0.f);
        u32 rows0[4] = {r0.x, r0.y, r0.z, r0.w};
        u32 rows1[4] = {r1.x, r1.y, r1.z, r1.w};
        u32 sb = 0, nb = 0;
#pragma unroll
        for (int j = 0; j < 4; ++j) {
            u32 a = rows0[j], bw = rows1[j];
#pragma unroll
            for (int kk = 0; kk < 2; ++kk) {
                int sh0 = 24 - 16 * kk, sh1 = 16 - 16 * kk;
                int a0 = (int)(a  << sh0) >> 24, a1 = (int)(a  << sh1) >> 24;
                int a2 = (int)(bw << sh0) >> 24, a3 = (int)(bw << sh1) >> 24;
                int raw = pos ? max(max(a0, a1), max(a2, a3))
                              : min(min(a0, a1), min(a2, a3));
                float v = ((float)raw - s.x) * s.y + s.z;
                int ow = j * 2 + kk;
                sb |= (u32)(v > 0.f) << (ow + 1);
                nb |= (u32)(v != 0.f) << (ow + 1);
            }
        }
        lspk[c * 12 + 1 + oh] = sb;
        lnpk[c * 12 + 1 + oh] = nb;
        if (oh < 4) {
            int zs = (oh == 0) ? 0 : (8 + oh);
            lspk[c * 12 + zs] = 0; lnpk[c * 12 + zs] = 0;
        }
    }
    __syncthreads();
#pragma unroll
    for (int k = 0; k < 2; ++k) {
        int e = t + k * 512;
        int g = e >> 3, h = e & 7;
        const u32* sp = lspk + (2 * g) * 12 + h;
        const u32* np = lnpk + (2 * g) * 12 + h;
        u32 S[8], N[8];
#pragma unroll
        for (int jc = 0; jc < 2; ++jc)
#pragma unroll
            for (int jj = 0; jj < 4; ++jj) {
                S[jc * 4 + jj] = sp[jc * 12 + jj];
                N[jc * 4 + jj] = np[jc * 12 + jj];
            }
        const u32* wq = wpk + (size_t)(2 * g) * 8;
        u32 Ws0[8], Wn0[8], Ws1[8], Wn1[8];
#pragma unroll
        for (int r = 0; r < 8; ++r) {
            u32 a = wq[r];      Ws0[r] = a & 15u;  Wn0[r] = (a >> 8) & 15u;
            u32 bb = wq[8 + r]; Ws1[r] = bb & 15u; Wn1[r] = (bb >> 8) & 15u;
        }
        int v0[8], v1[8];
        int s0 = 0, q0 = 0, s1 = 0, q1 = 0;
#pragma unroll
        for (int w = 0; w < 8; ++w) {
            int snz0 = 0, smis0 = 0, snz1 = 0, smis1 = 0;
#pragma unroll
            for (int r = 0; r < 8; ++r) {
                u32 ss = (S[r] >> w) & 15u;
                u32 nn = (N[r] >> w) & 15u;
                u32 nz0 = nn & Wn0[r]; u32 m0 = (ss ^ Ws0[r]) & nz0;
                snz0 += __popc(nz0); smis0 += __popc(m0);
                u32 nz1 = nn & Wn1[r]; u32 m1 = (ss ^ Ws1[r]) & nz1;
                snz1 += __popc(nz1); smis1 += __popc(m1);
            }
            v0[w] = snz0 - 2 * smis0;
            v1[w] = snz1 - 2 * smis1;
            s0 += v0[w]; q0 += v0[w] * v0[w];
            s1 += v1[w]; q1 += v1[w] * v1[w];
        }
#pragma unroll
        for (int m = 1; m < 8; m <<= 1) {
            s0 += __shfl_xor(s0, m); q0 += __shfl_xor(q0, m);
            s1 += __shfl_xor(s1, m); q1 += __shfl_xor(q1, m);
        }
        if (h == 0) {
            part[((size_t)(2 * g) * 512 + b) * 2]         = (double)s0;
            part[((size_t)(2 * g) * 512 + b) * 2 + 1]     = (double)q0;
            part[((size_t)(2 * g + 1) * 512 + b) * 2]     = (double)s1;
            part[((size_t)(2 * g + 1) * 512 + b) * 2 + 1] = (double)q1;
        }
        signed char* o0 = out + ((size_t)((b * 256 + 2 * g) * 8 + h)) * 8;
        signed char* o1 = o0 + 64;
        *(uint2*)o0 = make_uint2(pack4(v0[0], v0[1], v0[2], v0[3]),
                                 pack4(v0[4], v0[5], v0[6], v0[7]));
        *(uint2*)o1 = make_uint2(pack4(v1[0], v1[1], v1[2], v1[3]),
                                 pack4(v1[4], v1[5], v1[6], v1[7]));
    }
}

// --- FUSED: bn+binarize+channel-pack (LDS) -> 1x1 conv Cin=256, int16 out ---
__global__ __launch_bounds__(256) void k_fuse4(const signed char* __restrict__ q8,
                                               const float4* __restrict__ st,
                                               const u32* __restrict__ wp,
                                               short* __restrict__ out)
{
    __shared__ u32 sq[4096];       // one image: 256ch x 64hw bytes
    __shared__ u32 act[64 * 17];   // [hw][16 words], pad 17
    int b = blockIdx.x, t = threadIdx.x;
    const u32* qb = (const u32*)(q8 + (size_t)b * 16384);
    for (int i = t; i < 4096; i += 256) sq[i] = qb[i];
    __syncthreads();
    {
        const signed char* s8p = (const signed char*)sq;
        int hw = t & 63, qd = t >> 6;
        u32 sv0 = 0, nv0 = 0, sv1 = 0, nv1 = 0;
#pragma unroll
        for (int k = 0; k < 32; ++k) {
            int c = qd * 64 + k;
            float4 s = st[c];
            float v = ((float)s8p[c * 64 + hw] - s.x) * s.y + s.z;
            sv0 |= (u32)(v > 0.f) << k;
            nv0 |= (u32)(v != 0.f) << k;
        }
#pragma unroll
        for (int k = 0; k < 32; ++k) {
            int c = qd * 64 + 32 + k;
            float4 s = st[c];
            float v = ((float)s8p[c * 64 + hw] - s.x) * s.y + s.z;
            sv1 |= (u32)(v > 0.f) << k;
            nv1 |= (u32)(v != 0.f) << k;
        }
        u32* ap = act + hw * 17;
        ap[qd * 2]     = sv0;
        ap[qd * 2 + 1] = sv1;
        ap[8 + qd * 2]     = nv0;
        ap[8 + qd * 2 + 1] = nv1;
    }
    __syncthreads();
    int hw = t & 63, ch = t >> 6;
    const u32* ap = act + hw * 17;
    u32 as[8], an[8];
#pragma unroll
    for (int j = 0; j < 8; ++j) { as[j] = ap[j]; an[j] = ap[8 + j]; }
    short* op = out + (size_t)b * 256 * 64 + hw;
#pragma unroll 4
    for (int oc = ch * 64; oc < ch * 64 + 64; ++oc) {
        const u32* wq = wp + oc * 16;
        int snz = 0, smis = 0;
#pragma unroll
        for (int j = 0; j < 8; ++j) {
            u32 nz = an[j] & wq[8 + j];
            u32 m = (as[j] ^ wq[j]) & nz;
            snz += __popc(nz); smis += __popc(m);
        }
        op[(size_t)oc * 64] = (short)(snz - 2 * smis);
    }
}

// --- FC: block per image, bn3_2 applied inline, features read once ---
__global__ __launch_bounds__(256) void k_fc2(const short* __restrict__ f,
                                             const float4* __restrict__ st,
                                             const float* __restrict__ fcw,
                                             const float* __restrict__ fcb,
                                             float* __restrict__ out)
{
    int b = blockIdx.x, t = threadIdx.x;
    int lane = t & 63, wv = t >> 6;
    const u32* fp = (const u32*)(f + (size_t)b * 16384);
    float acc[10];
#pragma unroll
    for (int n = 0; n < 10; ++n) acc[n] = 0.f;
    for (int i = 0; i < 32; ++i) {
        int j = i * 256 + t;                 // u32 index; features 2j, 2j+1
        u32 v = fp[j];
        float4 s = st[j >> 5];               // channel = (2j)>>6 = j>>5
        float f0 = ((float)((int)(v << 16) >> 16) - s.x) * s.y + s.z;
        float f1 = ((float)((int)v >> 16) - s.x) * s.y + s.z;
#pragma unroll
        for (int n = 0; n < 10; ++n) {
            float2 wv2 = *(const float2*)(fcw + (size_t)n * 16384 + 2 * j);
            acc[n] += f0 * wv2.x + f1 * wv2.y;
        }
    }
#pragma unroll
    for (int n = 0; n < 10; ++n)
#pragma unroll
        for (int m = 1; m < 64; m <<= 1) acc[n] += __shfl_xor(acc[n], m);
    __shared__ float sred[4][10];
    if (lane == 0)
#pragma unroll
        for (int n = 0; n < 10; ++n) sred[wv][n] = acc[n];
    __syncthreads();
    if (t < 10)
        out[b * 10 + t] = sred[0][t] + sred[1][t] + sred[2][t] + sred[3][t] + fcb[t];
}

extern "C" void kernel_launch(void* const* d_in, const int* in_sizes, int n_in,
                              void* d_out, int out_size, void* d_ws, size_t ws_size,
                              hipStream_t stream)
{
    const float* x    = (const float*)d_in[0];
    const float* w1   = (const float*)d_in[1];
    const float* g1   = (const float*)d_in[2];
    const float* b1   = (const float*)d_in[3];
    const float* w2_1 = (const float*)d_in[4];
    const float* g2_1 = (const float*)d_in[5];
    const float* b2_1 = (const float*)d_in[6];
    const float* w2_2 = (const float*)d_in[7];
    const float* g2_2 = (const float*)d_in[8];
    const float* b2_2 = (const float*)d_in[9];
    const float* w3_1 = (const float*)d_in[10];
    const float* g3_1 = (const float*)d_in[11];
    const float* b3_1 = (const float*)d_in[12];
    const float* w3_2 = (const float*)d_in[13];
    const float* g3_2 = (const float*)d_in[14];
    const float* b3_2 = (const float*)d_in[15];
    const float* fcw  = (const float*)d_in[16];
    const float* fcb  = (const float*)d_in[17];
    float* out = (float*)d_out;

    // workspace layout (bytes). ppool aliases later c22 (write-after-consume
    // ordering per launch sequence).
    const size_t OFF_PPOOL= 0;          // 33,554,432  (-> c22 later)
    const size_t OFF_F3   = 33554432;   // 16,777,216  conv3_2 int16 out
    const size_t OFF_Q    = 50331648;   //  8,388,608  convg int8 outs
    const size_t OFF_WPK21= 67108864;   //  2,048
    const size_t OFF_WPK31= 67110912;   //  8,192
    const size_t OFF_WP22 = 67119104;   //  4,096
    const size_t OFF_WP32 = 67123200;   //  16,384
    const size_t OFF_PART = 67139584;   //  2,097,152
    const size_t OFF_ST   = 69236736;   //  20,480     5 x 256 float4
    const size_t OFF_SWT  = 69257216;   //  12,288     conv1 signed weights, tap-major f32
    const size_t OFF_XPAD = 69269504;   //  7,741,440  padded input [512*3][35][36]
    const size_t NEED     = OFF_XPAD + 7741440;
    if (ws_size < NEED) return;

    char* ws = (char*)d_ws;
    float* ppool = (float*)(ws + OFF_PPOOL);
    signed char* c22 = (signed char*)(ws + OFF_PPOOL); // after k_fuse2 consumes ppool
    short* f3  = (short*)(ws + OFF_F3);
    signed char* q8 = (signed char*)(ws + OFF_Q);
    u32* wpk21 = (u32*)(ws + OFF_WPK21);
    u32* wpk31 = (u32*)(ws + OFF_WPK31);
    u32* wp22  = (u32*)(ws + OFF_WP22);
    u32* wp32  = (u32*)(ws + OFF_WP32);
    double* part = (double*)(ws + OFF_PART);
    float4* st1  = (float4*)(ws + OFF_ST);
    float4* st21 = st1 + 256;
    float4* st22 = st21 + 256;
    float4* st31 = st22 + 256;
    float4* st32 = st31 + 256;
    float* swt   = (float*)(ws + OFF_SWT);
    float* xpad  = (float*)(ws + OFF_XPAD);

    // ---- weight prep + input pad (one launch) ----
    k_wprep<<<7574, 256, 0, stream>>>(w1, swt, w2_1, wpk21, w3_1, wpk31,
                                      w2_2, wp22, w3_2, wp32, x, xpad);

    // ---- layer 1 ----
    k_conv1f<<<4096, 256, 0, stream>>>(xpad, swt, g1, ppool, part);
    k_finalize2<<<64, 256, 0, stream>>>(part, 512, 512 * 1024, g1, b1, st1);

    // ---- layer 2 (pack+gconv fused) ----
    k_fuse2<<<512, 512, 0, stream>>>(ppool, st1, wpk21, q8, part);
    k_finalize2<<<64, 256, 0, stream>>>(part, 512, 512 * 256, g2_1, b2_1, st21);
    k_conv1x1_bp2<<<512, 256, 0, stream>>>(q8, st21, wp22, c22);
    k_statsfin8<<<256, 256, 0, stream>>>(c22, g2_2, b2_2, st22);

    // ---- layer 3 (pool+pack+gconv fused; pack+1x1 fused) ----
    k_fuse3<<<512, 512, 0, stream>>>(c22, st22, wpk31, q8, part);
    k_finalize2<<<256, 256, 0, stream>>>(part, 512, 512 * 64, g3_1, b3_1, st31);
    k_fuse4<<<512, 256, 0, stream>>>(q8, st31, wp32, f3);
    k_statsfin16<<<256, 256, 0, stream>>>(f3, g3_2, b3_2, st32);

    // ---- FC (bn3_2 inline) ----
    k_fc2<<<512, 256, 0, stream>>>(f3, st32, fcw, fcb, out);
}

// Round 17
// 194.535 us; speedup vs baseline: 1.6998x; 1.2426x over previous
//
#include <hip/hip_runtime.h>

typedef unsigned int u32;

// ---------------------------------------------------------------------------
// LiBNet forward, bit-packed ternary arithmetic + integer intermediates.
// dot over taps = popc(nzA & nzW) - 2*popc((sA ^ sW) & nzA & nzW)
// conv1: thread = 2x2 pooled window x 8 oc, fmaf chains, global/L2 padded
// input (LDS staging measured worse). Pack->conv fused per image; mid
// kernels split along channels/groups for TLP (were 1-2 waves/SIMD).
// ---------------------------------------------------------------------------

static __device__ __forceinline__ float fsign(float x) {
    return (x > 0.f) ? 1.f : ((x < 0.f) ? -1.f : 0.f);
}
static __device__ __forceinline__ u32 pack4(int a, int b, int c, int d) {
    return (a & 0xff) | ((b & 0xff) << 8) | ((c & 0xff) << 16) | ((u32)(d & 0xff) << 24);
}
// DPP on float (VALU pipe). 0xB1 = quad lane^1, 0x4E = quad lane^2,
// 0x124 = row_ror:4, 0x128 = row_ror:8 (16-lane row rotations).
template <int CTRL>
static __device__ __forceinline__ float dppf(float x) {
    int i = __builtin_amdgcn_mov_dpp(__float_as_int(x), CTRL, 0xF, 0xF, true);
    return __int_as_float(i);
}

// --- weight prep + input padding (one launch) ---
__global__ __launch_bounds__(256) void k_wprep(const float* __restrict__ w1, float* __restrict__ swt,
                                               const float* __restrict__ w2_1, u32* __restrict__ wpk21,
                                               const float* __restrict__ w3_1, u32* __restrict__ wpk31,
                                               const float* __restrict__ w2_2, u32* __restrict__ wp22,
                                               const float* __restrict__ w3_2, u32* __restrict__ wp32,
                                               const float* __restrict__ x, float* __restrict__ xpad)
{
    int blk = blockIdx.x, tid = threadIdx.x;
    if (blk >= 14) {                    // pad x -> xpad [512*3][35][36]
        int i = (blk - 14) * 256 + tid;
        if (i < 1935360) {
            int bic = i / 1260;
            int rem = i - bic * 1260;
            int r = rem / 36, c = rem - r * 36;
            float v = 0.f;
            if (r >= 1 && r <= 32 && c >= 1 && c <= 32)
                v = x[bic * 1024 + (r - 1) * 32 + (c - 1)];
            xpad[i] = v;
        }
        return;
    }
    if (blk < 12) {
        int i = blk * 256 + tid;
        if (i < 3072) {
            int k = i >> 6, oc = i & 63;
            swt[i] = fsign(w1[oc * 48 + k]);   // tap-major
        }
        return;
    }
    if (blk == 12) {
        if (tid < 64) {   // grouped 4x4 weights, C=64
            const float* p = w2_1 + tid * 32;
            for (int r = 0; r < 8; ++r) {
                u32 sn = 0, nz = 0;
                for (int kw = 0; kw < 4; ++kw) {
                    float v = p[r * 4 + kw];
                    sn |= (u32)(v > 0.f) << kw;
                    nz |= (u32)(v != 0.f) << kw;
                }
                wpk21[tid * 8 + r] = sn | (nz << 8);
            }
        }
        {                 // 1x1 weights 256x64
            const float* p = w2_2 + (size_t)tid * 64;
            for (int j = 0; j < 2; ++j) {
                u32 sv = 0, nv = 0;
                for (int k = 0; k < 32; ++k) {
                    float v = p[j * 32 + k];
                    sv |= (u32)(v > 0.f) << k;
                    nv |= (u32)(v != 0.f) << k;
                }
                wp22[tid * 4 + j] = sv;
                wp22[tid * 4 + 2 + j] = nv;
            }
        }
        return;
    }
    {                     // blk == 13
        {                 // grouped 4x4 weights, C=256
            const float* p = w3_1 + tid * 32;
            for (int r = 0; r < 8; ++r) {
                u32 sn = 0, nz = 0;
                for (int kw = 0; kw < 4; ++kw) {
                    float v = p[r * 4 + kw];
                    sn |= (u32)(v > 0.f) << kw;
                    nz |= (u32)(v != 0.f) << kw;
                }
                wpk31[tid * 8 + r] = sn | (nz << 8);
            }
        }
        {                 // 1x1 weights 256x256
            const float* p = w3_2 + (size_t)tid * 256;
            for (int j = 0; j < 8; ++j) {
                u32 sv = 0, nv = 0;
                for (int k = 0; k < 32; ++k) {
                    float v = p[j * 32 + k];
                    sv |= (u32)(v > 0.f) << k;
                    nv |= (u32)(v != 0.f) << k;
                }
                wp32[tid * 16 + j] = sv;
                wp32[tid * 16 + 8 + j] = nv;
            }
        }
    }
}

// --- conv1 fused: block = (image, oc-group of 8); thread = 2x2 pool window ---
__global__ __launch_bounds__(256) void k_conv1f(const float* __restrict__ xpad,
                                                const float* __restrict__ swt,
                                                const float* __restrict__ g1,
                                                float* __restrict__ ppool,
                                                double* __restrict__ part)
{
    __shared__ float sacc_s[8 * 17];    // [j][16 s16-partials], pad 17
    __shared__ float sacc_q[8 * 17];
    int b = blockIdx.x >> 3, ocg = blockIdx.x & 7;
    int t = threadIdx.x;
    int lane = t & 63, wv = t >> 6;
    int oh = t >> 4, ow = t & 15;       // pooled position
    const float* xb = xpad + (size_t)b * 3780 + (2 * oh) * 36 + 2 * ow;
    float acc0[8], acc1[8], acc2[8], acc3[8];   // [pos(r,c)][oc j]
#pragma unroll
    for (int j = 0; j < 8; ++j) { acc0[j] = 0.f; acc1[j] = 0.f; acc2[j] = 0.f; acc3[j] = 0.f; }
#pragma unroll 1
    for (int ic = 0; ic < 3; ++ic) {
        const float* xr = xb + ic * 1260;
        const float* wic = swt + ic * 1024 + ocg * 8;
#pragma unroll 1
        for (int rr = 0; rr < 5; ++rr) {
            float2 a01 = *(const float2*)xr;
            float2 a23 = *(const float2*)(xr + 2);
            float x0 = a01.x, x1 = a01.y, x2 = a23.x, x3 = a23.y, x4 = xr[4];
            if (rr <= 3) {              // out-row 2oh via kh=rr
                const float* wA = wic + rr * 256;
#pragma unroll
                for (int j = 0; j < 8; ++j) {
                    float w0 = wA[j], w1 = wA[64 + j], w2 = wA[128 + j], w3 = wA[192 + j];
                    acc0[j] = __builtin_fmaf(x0, w0, acc0[j]);
                    acc0[j] = __builtin_fmaf(x1, w1, acc0[j]);
                    acc0[j] = __builtin_fmaf(x2, w2, acc0[j]);
                    acc0[j] = __builtin_fmaf(x3, w3, acc0[j]);
                    acc1[j] = __builtin_fmaf(x1, w0, acc1[j]);
                    acc1[j] = __builtin_fmaf(x2, w1, acc1[j]);
                    acc1[j] = __builtin_fmaf(x3, w2, acc1[j]);
                    acc1[j] = __builtin_fmaf(x4, w3, acc1[j]);
                }
            }
            if (rr >= 1) {              // out-row 2oh+1 via kh=rr-1
                const float* wB = wic + (rr - 1) * 256;
#pragma unroll
                for (int j = 0; j < 8; ++j) {
                    float w0 = wB[j], w1 = wB[64 + j], w2 = wB[128 + j], w3 = wB[192 + j];
                    acc2[j] = __builtin_fmaf(x0, w0, acc2[j]);
                    acc2[j] = __builtin_fmaf(x1, w1, acc2[j]);
                    acc2[j] = __builtin_fmaf(x2, w2, acc2[j]);
                    acc2[j] = __builtin_fmaf(x3, w3, acc2[j]);
                    acc3[j] = __builtin_fmaf(x1, w0, acc3[j]);
                    acc3[j] = __builtin_fmaf(x2, w1, acc3[j]);
                    acc3[j] = __builtin_fmaf(x3, w2, acc3[j]);
                    acc3[j] = __builtin_fmaf(x4, w3, acc3[j]);
                }
            }
            xr += 36;
        }
    }
    bool owner16 = ((lane & 15) == 0);
    float* ppb = ppool + ((size_t)(b * 64 + ocg * 8)) * 256 + t;
#pragma unroll
    for (int j = 0; j < 8; ++j) {
        float a0 = acc0[j], a1 = acc1[j], a2 = acc2[j], a3 = acc3[j];
        bool posi = (g1[ocg * 8 + j] > 0.f);    // == sign(bn scale), uniform
        float pooled = posi ? fmaxf(fmaxf(a0, a1), fmaxf(a2, a3))
                            : fminf(fminf(a0, a1), fminf(a2, a3));
        float s = (a0 + a1) + (a2 + a3);
        float sq = a0 * a0 + a1 * a1 + a2 * a2 + a3 * a3;
        s += dppf<0xB1>(s);   sq += dppf<0xB1>(sq);
        s += dppf<0x4E>(s);   sq += dppf<0x4E>(sq);
        s += dppf<0x124>(s);  sq += dppf<0x124>(sq);
        s += dppf<0x128>(s);  sq += dppf<0x128>(sq);
        if (owner16) {
            int idx = j * 17 + wv * 4 + (lane >> 4);
            sacc_s[idx] = s;
            sacc_q[idx] = sq;
        }
        ppb[j * 256] = pooled;
    }
    __syncthreads();
    if (t < 16) {
        int j = t >> 1, half = t & 1;
        const float* sp = (half ? sacc_q : sacc_s) + j * 17;
        double acc = 0.0;
        for (int i = 0; i < 16; ++i) acc += (double)sp[i];
        part[(((size_t)(ocg * 8 + j)) * 512 + b) * 2 + half] = acc;
    }
}

// --- finalize: block per channel; mean/var -> power-of-two shift scale ---
__global__ __launch_bounds__(256) void k_finalize2(const double* __restrict__ part,
                                                   int nch, int N,
                                                   const float* __restrict__ gamma,
                                                   const float* __restrict__ beta,
                                                   float4* __restrict__ st)
{
    int c = blockIdx.x;
    double s = 0.0, sq = 0.0;
    for (int i = threadIdx.x; i < nch; i += 256) {
        s  += part[((size_t)c * nch + i) * 2];
        sq += part[((size_t)c * nch + i) * 2 + 1];
    }
    __shared__ double ss[256];
    __shared__ double sb[256];
    ss[threadIdx.x] = s; sb[threadIdx.x] = sq;
    __syncthreads();
    for (int stp = 128; stp > 0; stp >>= 1) {
        if (threadIdx.x < stp) {
            ss[threadIdx.x] += ss[threadIdx.x + stp];
            sb[threadIdx.x] += sb[threadIdx.x + stp];
        }
        __syncthreads();
    }
    if (threadIdx.x == 0) {
        double mean = ss[0] / (double)N;
        double var = sb[0] / (double)N - mean * mean;
        float inv = gamma[c] / sqrtf((float)var + 1e-5f);
        float sh = rintf(log2f(fabsf(inv) + 1e-12f));
        sh = fminf(fmaxf(sh, -4.f), 4.f);
        float scale = copysignf(exp2f(sh), inv);
        st[c] = make_float4((float)mean, scale, beta[c], 0.f);
    }
}

// --- merged stats+finalize, int8 tensor [512][256][256] per channel ---
__global__ __launch_bounds__(1024) void k_statsfin8(const signed char* __restrict__ in,
                                                    const float* __restrict__ gamma,
                                                    const float* __restrict__ beta,
                                                    float4* __restrict__ st)
{
    int c = blockIdx.x;
    int s = 0, sq = 0;
    for (int i = threadIdx.x; i < 32768; i += 1024) {   // 512 b x 64 words
        int b = i >> 6, w = i & 63;
        u32 v = ((const u32*)in)[((size_t)(b * 256 + c) << 6) + w];
        int x0 = (int)(v << 24) >> 24, x1 = (int)(v << 16) >> 24;
        int x2 = (int)(v << 8) >> 24,  x3 = (int)v >> 24;
        s += x0 + x1 + x2 + x3;
        sq += x0 * x0 + x1 * x1 + x2 * x2 + x3 * x3;
    }
    __shared__ int ss[1024];
    __shared__ int sb[1024];
    ss[threadIdx.x] = s; sb[threadIdx.x] = sq;
    __syncthreads();
    for (int stp = 512; stp > 0; stp >>= 1) {
        if (threadIdx.x < stp) {
            ss[threadIdx.x] += ss[threadIdx.x + stp];
            sb[threadIdx.x] += sb[threadIdx.x + stp];
        }
        __syncthreads();
    }
    if (threadIdx.x == 0) {
        double mean = (double)ss[0] / 131072.0;
        double var = (double)sb[0] / 131072.0 - mean * mean;
        float inv = gamma[c] / sqrtf((float)var + 1e-5f);
        float sh = rintf(log2f(fabsf(inv) + 1e-12f));
        sh = fminf(fmaxf(sh, -4.f), 4.f);
        float scale = copysignf(exp2f(sh), inv);
        st[c] = make_float4((float)mean, scale, beta[c], 0.f);
    }
}

// --- merged stats+finalize, int16 tensor [512][256][64] per channel ---
__global__ __launch_bounds__(1024) void k_statsfin16(const short* __restrict__ in,
                                                     const float* __restrict__ gamma,
                                                     const float* __restrict__ beta,
                                                     float4* __restrict__ st)
{
    int c = blockIdx.x;
    int s = 0, sq = 0;
    for (int i = threadIdx.x; i < 16384; i += 1024) {   // 512 b x 32 words
        int b = i >> 5, w = i & 31;
        u32 v = ((const u32*)in)[((size_t)(b * 256 + c) << 5) + w];
        int x0 = (int)(v << 16) >> 16, x1 = (int)v >> 16;
        s += x0 + x1;
        sq += x0 * x0 + x1 * x1;
    }
    __shared__ double ss[1024];
    __shared__ double sb[1024];
    ss[threadIdx.x] = (double)s; sb[threadIdx.x] = (double)sq;
    __syncthreads();
    for (int stp = 512; stp > 0; stp >>= 1) {
        if (threadIdx.x < stp) {
            ss[threadIdx.x] += ss[threadIdx.x + stp];
            sb[threadIdx.x] += sb[threadIdx.x + stp];
        }
        __syncthreads();
    }
    if (threadIdx.x == 0) {
        double mean = ss[0] / 32768.0;
        double var = sb[0] / 32768.0 - mean * mean;
        float inv = gamma[c] / sqrtf((float)var + 1e-5f);
        float sh = rintf(log2f(fabsf(inv) + 1e-12f));
        sh = fminf(fmaxf(sh, -4.f), 4.f);
        float scale = copysignf(exp2f(sh), inv);
        st[c] = make_float4((float)mean, scale, beta[c], 0.f);
    }
}

// --- FUSED layer-2 head: block = (image, channel-half of 32). 256 thr. ---
__global__ __launch_bounds__(256) void k_fuse2(const float* __restrict__ ppool,
                                               const float4* __restrict__ st,
                                               const u32* __restrict__ wpk,
                                               signed char* __restrict__ out,
                                               double* __restrict__ part)
{
    __shared__ u32 lspk[32 * 20];
    __shared__ u32 lnpk[32 * 20];
    int b = blockIdx.x >> 1, half = blockIdx.x & 1;
    int t = threadIdx.x;
    // phase 1: bn + binarize + row-pack, 32 ch x 16 rows (2 items/thread)
#pragma unroll
    for (int k = 0; k < 2; ++k) {
        int e = t + k * 256;
        int cl = e >> 4, oh = e & 15;
        int c = half * 32 + cl;
        float4 s = st[c];
        const float4* p = (const float4*)(ppool + ((size_t)(b * 64 + c)) * 256 + oh * 16);
        u32 sb = 0, nb = 0;
#pragma unroll
        for (int j = 0; j < 4; ++j) {
            float4 v4 = p[j];
            float vs[4] = {v4.x, v4.y, v4.z, v4.w};
#pragma unroll
            for (int kk = 0; kk < 4; ++kk) {
                float v = (vs[kk] - s.x) * s.y + s.z;
                int ow = j * 4 + kk;
                sb |= (u32)(v > 0.f) << (ow + 1);
                nb |= (u32)(v != 0.f) << (ow + 1);
            }
        }
        lspk[cl * 20 + 1 + oh] = sb;
        lnpk[cl * 20 + 1 + oh] = nb;
        if (oh < 4) {
            int zs = (oh == 0) ? 0 : (16 + oh);
            lspk[cl * 20 + zs] = 0; lnpk[cl * 20 + zs] = 0;
        }
    }
    __syncthreads();
    // phase 2: grouped conv, 16 groups x 16 rows (1 item/thread)
    int gl = t >> 4, h = t & 15;
    int g = half * 16 + gl;
    const u32* sp = lspk + (2 * gl) * 20 + h;
    const u32* np = lnpk + (2 * gl) * 20 + h;
    u32 S[8], N[8];
#pragma unroll
    for (int jc = 0; jc < 2; ++jc)
#pragma unroll
        for (int jj = 0; jj < 4; ++jj) {
            S[jc * 4 + jj] = sp[jc * 20 + jj];
            N[jc * 4 + jj] = np[jc * 20 + jj];
        }
    const u32* wq = wpk + (size_t)(2 * g) * 8;
    u32 Ws0[8], Wn0[8], Ws1[8], Wn1[8];
#pragma unroll
    for (int r = 0; r < 8; ++r) {
        u32 a = wq[r];      Ws0[r] = a & 15u;  Wn0[r] = (a >> 8) & 15u;
        u32 bb = wq[8 + r]; Ws1[r] = bb & 15u; Wn1[r] = (bb >> 8) & 15u;
    }
    int v0[16], v1[16];
    int s0 = 0, q0 = 0, s1 = 0, q1 = 0;
#pragma unroll
    for (int w = 0; w < 16; ++w) {
        int snz0 = 0, smis0 = 0, snz1 = 0, smis1 = 0;
#pragma unroll
        for (int r = 0; r < 8; ++r) {
            u32 ss = (S[r] >> w) & 15u;
            u32 nn = (N[r] >> w) & 15u;
            u32 nz0 = nn & Wn0[r]; u32 m0 = (ss ^ Ws0[r]) & nz0;
            snz0 += __popc(nz0); smis0 += __popc(m0);
            u32 nz1 = nn & Wn1[r]; u32 m1 = (ss ^ Ws1[r]) & nz1;
            snz1 += __popc(nz1); smis1 += __popc(m1);
        }
        v0[w] = snz0 - 2 * smis0;
        v1[w] = snz1 - 2 * smis1;
        s0 += v0[w]; q0 += v0[w] * v0[w];
        s1 += v1[w]; q1 += v1[w] * v1[w];
    }
#pragma unroll
    for (int m = 1; m < 16; m <<= 1) {
        s0 += __shfl_xor(s0, m); q0 += __shfl_xor(q0, m);
        s1 += __shfl_xor(s1, m); q1 += __shfl_xor(q1, m);
    }
    if (h == 0) {
        part[((size_t)(2 * g) * 512 + b) * 2]         = (double)s0;
        part[((size_t)(2 * g) * 512 + b) * 2 + 1]     = (double)q0;
        part[((size_t)(2 * g + 1) * 512 + b) * 2]     = (double)s1;
        part[((size_t)(2 * g + 1) * 512 + b) * 2 + 1] = (double)q1;
    }
    signed char* o0 = out + ((size_t)((b * 64 + 2 * g) * 16 + h)) * 16;
    signed char* o1 = o0 + 256;
    u32 wb0[4], wb1[4];
#pragma unroll
    for (int j = 0; j < 4; ++j) {
        wb0[j] = pack4(v0[4*j], v0[4*j+1], v0[4*j+2], v0[4*j+3]);
        wb1[j] = pack4(v1[4*j], v1[4*j+1], v1[4*j+2], v1[4*j+3]);
    }
    *(uint4*)o0 = make_uint4(wb0[0], wb0[1], wb0[2], wb0[3]);
    *(uint4*)o1 = make_uint4(wb1[0], wb1[1], wb1[2], wb1[3]);
}

// --- 1x1 conv Cin=64->Cout=256 (oc halves), HW=256, FUSED bn binarize+pack ---
__global__ __launch_bounds__(256) void k_conv1x1_bp2(const signed char* __restrict__ q8,
                                                     const float4* __restrict__ st,
                                                     const u32* __restrict__ wp,
                                                     signed char* __restrict__ out)
{
    int b = blockIdx.x >> 1, hoc = blockIdx.x & 1;
    int hw = threadIdx.x;
    const signed char* qp = q8 + (size_t)b * 64 * 256 + hw;
    u32 as0 = 0, as1 = 0, an0 = 0, an1 = 0;
#pragma unroll
    for (int k = 0; k < 32; ++k) {
        float4 s = st[k];                       // uniform -> s_load
        float v = ((float)qp[k * 256] - s.x) * s.y + s.z;   // coalesced byte load
        as0 |= (u32)(v > 0.f) << k;
        an0 |= (u32)(v != 0.f) << k;
    }
#pragma unroll
    for (int k = 0; k < 32; ++k) {
        float4 s = st[32 + k];
        float v = ((float)qp[(32 + k) * 256] - s.x) * s.y + s.z;
        as1 |= (u32)(v > 0.f) << k;
        an1 |= (u32)(v != 0.f) << k;
    }
    signed char* op = out + (size_t)b * 256 * 256 + hw;
    int oc0 = hoc * 128;
#pragma unroll 8
    for (int oc = oc0; oc < oc0 + 128; ++oc) {
        uint4 wv = ((const uint4*)wp)[oc];      // wave-uniform -> scalar loads
        u32 nz0 = an0 & wv.z, nz1 = an1 & wv.w;
        u32 m0 = (as0 ^ wv.x) & nz0, m1 = (as1 ^ wv.y) & nz1;
        int dot = __popc(nz0) + __popc(nz1) - 2 * (__popc(m0) + __popc(m1));
        op[(size_t)oc << 8] = (signed char)dot;
    }
}

// --- FUSED layer-3 head: block = (image, quarter of 64 ch / 32 groups). ---
__global__ __launch_bounds__(256) void k_fuse3(const signed char* __restrict__ c22,
                                               const float4* __restrict__ st,
                                               const u32* __restrict__ wpk,
                                               signed char* __restrict__ out,
                                               double* __restrict__ part)
{
    __shared__ u32 lspk[64 * 12];
    __shared__ u32 lnpk[64 * 12];
    int b = blockIdx.x >> 2, qd = blockIdx.x & 3;
    int t = threadIdx.x;
    // phase 1: bn+pool+binarize+pack, 64 ch x 8 rows (2 items/thread)
#pragma unroll
    for (int k = 0; k < 2; ++k) {
        int e = t + k * 256;
        int cl = e >> 3, oh = e & 7;
        int c = qd * 64 + cl;
        float4 s = st[c];
        const uint4* p = (const uint4*)(c22 + ((size_t)(b * 256 + c)) * 256 + (size_t)(2 * oh) * 16);
        uint4 r0 = p[0], r1 = p[1];
        bool pos = (s.y > 0.f);
        u32 rows0[4] = {r0.x, r0.y, r0.z, r0.w};
        u32 rows1[4] = {r1.x, r1.y, r1.z, r1.w};
        u32 sb = 0, nb = 0;
#pragma unroll
        for (int j = 0; j < 4; ++j) {
            u32 a = rows0[j], bw = rows1[j];
#pragma unroll
            for (int kk = 0; kk < 2; ++kk) {
                int sh0 = 24 - 16 * kk, sh1 = 16 - 16 * kk;
                int a0 = (int)(a  << sh0) >> 24, a1 = (int)(a  << sh1) >> 24;
                int a2 = (int)(bw << sh0) >> 24, a3 = (int)(bw << sh1) >> 24;
                int raw = pos ? max(max(a0, a1), max(a2, a3))
                              : min(min(a0, a1), min(a2, a3));
                float v = ((float)raw - s.x) * s.y + s.z;
                int ow = j * 2 + kk;
                sb |= (u32)(v > 0.f) << (ow + 1);
                nb |= (u32)(v != 0.f) << (ow + 1);
            }
        }
        lspk[cl * 12 + 1 + oh] = sb;
        lnpk[cl * 12 + 1 + oh] = nb;
        if (oh < 4) {
            int zs = (oh == 0) ? 0 : (8 + oh);
            lspk[cl * 12 + zs] = 0; lnpk[cl * 12 + zs] = 0;
        }
    }
    __syncthreads();
    // phase 2: grouped conv, 32 groups x 8 rows (1 item/thread)
    int gl = t >> 3, h = t & 7;
    int g = qd * 32 + gl;
    const u32* sp = lspk + (2 * gl) * 12 + h;
    const u32* np = lnpk + (2 * gl) * 12 + h;
    u32 S[8], N[8];
#pragma unroll
    for (int jc = 0; jc < 2; ++jc)
#pragma unroll
        for (int jj = 0; jj < 4; ++jj) {
            S[jc * 4 + jj] = sp[jc * 12 + jj];
            N[jc * 4 + jj] = np[jc * 12 + jj];
        }
    const u32* wq = wpk + (size_t)(2 * g) * 8;
    u32 Ws0[8], Wn0[8], Ws1[8], Wn1[8];
#pragma unroll
    for (int r = 0; r < 8; ++r) {
        u32 a = wq[r];      Ws0[r] = a & 15u;  Wn0[r] = (a >> 8) & 15u;
        u32 bb = wq[8 + r]; Ws1[r] = bb & 15u; Wn1[r] = (bb >> 8) & 15u;
    }
    int v0[8], v1[8];
    int s0 = 0, q0 = 0, s1 = 0, q1 = 0;
#pragma unroll
    for (int w = 0; w < 8; ++w) {
        int snz0 = 0, smis0 = 0, snz1 = 0, smis1 = 0;
#pragma unroll
        for (int r = 0; r < 8; ++r) {
            u32 ss = (S[r] >> w) & 15u;
            u32 nn = (N[r] >> w) & 15u;
            u32 nz0 = nn & Wn0[r]; u32 m0 = (ss ^ Ws0[r]) & nz0;
            snz0 += __popc(nz0); smis0 += __popc(m0);
            u32 nz1 = nn & Wn1[r]; u32 m1 = (ss ^ Ws1[r]) & nz1;
            snz1 += __popc(nz1); smis1 += __popc(m1);
        }
        v0[w] = snz0 - 2 * smis0;
        v1[w] = snz1 - 2 * smis1;
        s0 += v0[w]; q0 += v0[w] * v0[w];
        s1 += v1[w]; q1 += v1[w] * v1[w];
    }
#pragma unroll
    for (int m = 1; m < 8; m <<= 1) {
        s0 += __shfl_xor(s0, m); q0 += __shfl_xor(q0, m);
        s1 += __shfl_xor(s1, m); q1 += __shfl_xor(q1, m);
    }
    if (h == 0) {
        part[((size_t)(2 * g) * 512 + b) * 2]         = (double)s0;
        part[((size_t)(2 * g) * 512 + b) * 2 + 1]     = (double)q0;
        part[((size_t)(2 * g + 1) * 512 + b) * 2]     = (double)s1;
        part[((size_t)(2 * g + 1) * 512 + b) * 2 + 1] = (double)q1;
    }
    signed char* o0 = out + ((size_t)((b * 256 + 2 * g) * 8 + h)) * 8;
    signed char* o1 = o0 + 64;
    *(uint2*)o0 = make_uint2(pack4(v0[0], v0[1], v0[2], v0[3]),
                             pack4(v0[4], v0[5], v0[6], v0[7]));
    *(uint2*)o1 = make_uint2(pack4(v1[0], v1[1], v1[2], v1[3]),
                             pack4(v1[4], v1[5], v1[6], v1[7]));
}

// --- FUSED: bn+binarize+channel-pack (LDS) -> 1x1 conv Cin=256, int16 out ---
__global__ __launch_bounds__(256) void k_fuse4(const signed char* __restrict__ q8,
                                               const float4* __restrict__ st,
                                               const u32* __restrict__ wp,
                                               short* __restrict__ out)
{
    __shared__ u32 sq[4096];       // one image: 256ch x 64hw bytes
    __shared__ u32 act[64 * 17];   // [hw][16 words], pad 17
    int b = blockIdx.x, t = threadIdx.x;
    const u32* qb = (const u32*)(q8 + (size_t)b * 16384);
    for (int i = t; i < 4096; i += 256) sq[i] = qb[i];
    __syncthreads();
    {
        const signed char* s8p = (const signed char*)sq;
        int hw = t & 63, qd = t >> 6;
        u32 sv0 = 0, nv0 = 0, sv1 = 0, nv1 = 0;
#pragma unroll
        for (int k = 0; k < 32; ++k) {
            int c = qd * 64 + k;
            float4 s = st[c];
            float v = ((float)s8p[c * 64 + hw] - s.x) * s.y + s.z;
            sv0 |= (u32)(v > 0.f) << k;
            nv0 |= (u32)(v != 0.f) << k;
        }
#pragma unroll
        for (int k = 0; k < 32; ++k) {
            int c = qd * 64 + 32 + k;
            float4 s = st[c];
            float v = ((float)s8p[c * 64 + hw] - s.x) * s.y + s.z;
            sv1 |= (u32)(v > 0.f) << k;
            nv1 |= (u32)(v != 0.f) << k;
        }
        u32* ap = act + hw * 17;
        ap[qd * 2]     = sv0;
        ap[qd * 2 + 1] = sv1;
        ap[8 + qd * 2]     = nv0;
        ap[8 + qd * 2 + 1] = nv1;
    }
    __syncthreads();
    int hw = t & 63, ch = t >> 6;
    const u32* ap = act + hw * 17;
    u32 as[8], an[8];
#pragma unroll
    for (int j = 0; j < 8; ++j) { as[j] = ap[j]; an[j] = ap[8 + j]; }
    short* op = out + (size_t)b * 256 * 64 + hw;
#pragma unroll 4
    for (int oc = ch * 64; oc < ch * 64 + 64; ++oc) {
        const u32* wq = wp + oc * 16;
        int snz = 0, smis = 0;
#pragma unroll
        for (int j = 0; j < 8; ++j) {
            u32 nz = an[j] & wq[8 + j];
            u32 m = (as[j] ^ wq[j]) & nz;
            snz += __popc(nz); smis += __popc(m);
        }
        op[(size_t)oc * 64] = (short)(snz - 2 * smis);
    }
}

// --- FC: block per image (512 thr), bn3_2 inline, features read once ---
__global__ __launch_bounds__(512) void k_fc2(const short* __restrict__ f,
                                             const float4* __restrict__ st,
                                             const float* __restrict__ fcw,
                                             const float* __restrict__ fcb,
                                             float* __restrict__ out)
{
    int b = blockIdx.x, t = threadIdx.x;
    int lane = t & 63, wv = t >> 6;
    const u32* fp = (const u32*)(f + (size_t)b * 16384);
    float acc[10];
#pragma unroll
    for (int n = 0; n < 10; ++n) acc[n] = 0.f;
    for (int i = 0; i < 16; ++i) {
        int j = i * 512 + t;                 // u32 index; features 2j, 2j+1
        u32 v = fp[j];
        float4 s = st[j >> 5];               // channel = (2j)>>6 = j>>5
        float f0 = ((float)((int)(v << 16) >> 16) - s.x) * s.y + s.z;
        float f1 = ((float)((int)v >> 16) - s.x) * s.y + s.z;
#pragma unroll
        for (int n = 0; n < 10; ++n) {
            float2 wv2 = *(const float2*)(fcw + (size_t)n * 16384 + 2 * j);
            acc[n] += f0 * wv2.x + f1 * wv2.y;
        }
    }
#pragma unroll
    for (int n = 0; n < 10; ++n)
#pragma unroll
        for (int m = 1; m < 64; m <<= 1) acc[n] += __shfl_xor(acc[n], m);
    __shared__ float sred[8][10];
    if (lane == 0)
#pragma unroll
        for (int n = 0; n < 10; ++n) sred[wv][n] = acc[n];
    __syncthreads();
    if (t < 10) {
        float r = fcb[t];
#pragma unroll
        for (int w = 0; w < 8; ++w) r += sred[w][t];
        out[b * 10 + t] = r;
    }
}

extern "C" void kernel_launch(void* const* d_in, const int* in_sizes, int n_in,
                              void* d_out, int out_size, void* d_ws, size_t ws_size,
                              hipStream_t stream)
{
    const float* x    = (const float*)d_in[0];
    const float* w1   = (const float*)d_in[1];
    const float* g1   = (const float*)d_in[2];
    const float* b1   = (const float*)d_in[3];
    const float* w2_1 = (const float*)d_in[4];
    const float* g2_1 = (const float*)d_in[5];
    const float* b2_1 = (const float*)d_in[6];
    const float* w2_2 = (const float*)d_in[7];
    const float* g2_2 = (const float*)d_in[8];
    const float* b2_2 = (const float*)d_in[9];
    const float* w3_1 = (const float*)d_in[10];
    const float* g3_1 = (const float*)d_in[11];
    const float* b3_1 = (const float*)d_in[12];
    const float* w3_2 = (const float*)d_in[13];
    const float* g3_2 = (const float*)d_in[14];
    const float* b3_2 = (const float*)d_in[15];
    const float* fcw  = (const float*)d_in[16];
    const float* fcb  = (const float*)d_in[17];
    float* out = (float*)d_out;

    // workspace layout (bytes). ppool aliases later c22 (write-after-consume
    // ordering per launch sequence).
    const size_t OFF_PPOOL= 0;          // 33,554,432  (-> c22 later)
    const size_t OFF_F3   = 33554432;   // 16,777,216  conv3_2 int16 out
    const size_t OFF_Q    = 50331648;   //  8,388,608  convg int8 outs
    const size_t OFF_WPK21= 67108864;   //  2,048
    const size_t OFF_WPK31= 67110912;   //  8,192
    const size_t OFF_WP22 = 67119104;   //  4,096
    const size_t OFF_WP32 = 67123200;   //  16,384
    const size_t OFF_PART = 67139584;   //  2,097,152
    const size_t OFF_ST   = 69236736;   //  20,480     5 x 256 float4
    const size_t OFF_SWT  = 69257216;   //  12,288     conv1 signed weights, tap-major f32
    const size_t OFF_XPAD = 69269504;   //  7,741,440  padded input [512*3][35][36]
    const size_t NEED     = OFF_XPAD + 7741440;
    if (ws_size < NEED) return;

    char* ws = (char*)d_ws;
    float* ppool = (float*)(ws + OFF_PPOOL);
    signed char* c22 = (signed char*)(ws + OFF_PPOOL); // after k_fuse2 consumes ppool
    short* f3  = (short*)(ws + OFF_F3);
    signed char* q8 = (signed char*)(ws + OFF_Q);
    u32* wpk21 = (u32*)(ws + OFF_WPK21);
    u32* wpk31 = (u32*)(ws + OFF_WPK31);
    u32* wp22  = (u32*)(ws + OFF_WP22);
    u32* wp32  = (u32*)(ws + OFF_WP32);
    double* part = (double*)(ws + OFF_PART);
    float4* st1  = (float4*)(ws + OFF_ST);
    float4* st21 = st1 + 256;
    float4* st22 = st21 + 256;
    float4* st31 = st22 + 256;
    float4* st32 = st31 + 256;
    float* swt   = (float*)(ws + OFF_SWT);
    float* xpad  = (float*)(ws + OFF_XPAD);

    // ---- weight prep + input pad (one launch) ----
    k_wprep<<<7574, 256, 0, stream>>>(w1, swt, w2_1, wpk21, w3_1, wpk31,
                                      w2_2, wp22, w3_2, wp32, x, xpad);

    // ---- layer 1 ----
    k_conv1f<<<4096, 256, 0, stream>>>(xpad, swt, g1, ppool, part);
    k_finalize2<<<64, 256, 0, stream>>>(part, 512, 512 * 1024, g1, b1, st1);

    // ---- layer 2 (pack+gconv fused, channel-split) ----
    k_fuse2<<<1024, 256, 0, stream>>>(ppool, st1, wpk21, q8, part);
    k_finalize2<<<64, 256, 0, stream>>>(part, 512, 512 * 256, g2_1, b2_1, st21);
    k_conv1x1_bp2<<<1024, 256, 0, stream>>>(q8, st21, wp22, c22);
    k_statsfin8<<<256, 1024, 0, stream>>>(c22, g2_2, b2_2, st22);

    // ---- layer 3 (pool+pack+gconv fused, quarter-split; pack+1x1 fused) ----
    k_fuse3<<<2048, 256, 0, stream>>>(c22, st22, wpk31, q8, part);
    k_finalize2<<<256, 256, 0, stream>>>(part, 512, 512 * 64, g3_1, b3_1, st31);
    k_fuse4<<<512, 256, 0, stream>>>(q8, st31, wp32, f3);
    k_statsfin16<<<256, 1024, 0, stream>>>(f3, g3_2, b3_2, st32);

    // ---- FC (bn3_2 inline) ----
    k_fc2<<<512, 512, 0, stream>>>(f3, st32, fcw, fcb, out);
}

// Round 18
// 191.989 us; speedup vs baseline: 1.7224x; 1.0133x over previous
//
#include <hip/hip_runtime.h>

typedef unsigned int u32;

// ---------------------------------------------------------------------------
// LiBNet forward, bit-packed ternary arithmetic + integer intermediates.
// dot over taps = popc(nzA & nzW) - 2*popc((sA ^ sW) & nzA & nzW)
// conv1: thread = 2x2 pooled window x 8 oc, fmaf chains, rr loop fully
// unrolled (batches 25 row-loads + 20 weight s_loads per ic for ILP).
// Global/L2 padded input (LDS staging measured worse). Mid kernels
// channel-split for TLP.
// ---------------------------------------------------------------------------

static __device__ __forceinline__ float fsign(float x) {
    return (x > 0.f) ? 1.f : ((x < 0.f) ? -1.f : 0.f);
}
static __device__ __forceinline__ u32 pack4(int a, int b, int c, int d) {
    return (a & 0xff) | ((b & 0xff) << 8) | ((c & 0xff) << 16) | ((u32)(d & 0xff) << 24);
}
// DPP on float (VALU pipe). 0xB1 = quad lane^1, 0x4E = quad lane^2,
// 0x124 = row_ror:4, 0x128 = row_ror:8 (16-lane row rotations).
template <int CTRL>
static __device__ __forceinline__ float dppf(float x) {
    int i = __builtin_amdgcn_mov_dpp(__float_as_int(x), CTRL, 0xF, 0xF, true);
    return __int_as_float(i);
}

// --- weight prep + input padding (one launch) ---
__global__ __launch_bounds__(256) void k_wprep(const float* __restrict__ w1, float* __restrict__ swt,
                                               const float* __restrict__ w2_1, u32* __restrict__ wpk21,
                                               const float* __restrict__ w3_1, u32* __restrict__ wpk31,
                                               const float* __restrict__ w2_2, u32* __restrict__ wp22,
                                               const float* __restrict__ w3_2, u32* __restrict__ wp32,
                                               const float* __restrict__ x, float* __restrict__ xpad)
{
    int blk = blockIdx.x, tid = threadIdx.x;
    if (blk >= 14) {                    // pad x -> xpad [512*3][35][36]
        int i = (blk - 14) * 256 + tid;
        if (i < 1935360) {
            int bic = i / 1260;
            int rem = i - bic * 1260;
            int r = rem / 36, c = rem - r * 36;
            float v = 0.f;
            if (r >= 1 && r <= 32 && c >= 1 && c <= 32)
                v = x[bic * 1024 + (r - 1) * 32 + (c - 1)];
            xpad[i] = v;
        }
        return;
    }
    if (blk < 12) {
        int i = blk * 256 + tid;
        if (i < 3072) {
            int k = i >> 6, oc = i & 63;
            swt[i] = fsign(w1[oc * 48 + k]);   // tap-major
        }
        return;
    }
    if (blk == 12) {
        if (tid < 64) {   // grouped 4x4 weights, C=64
            const float* p = w2_1 + tid * 32;
            for (int r = 0; r < 8; ++r) {
                u32 sn = 0, nz = 0;
                for (int kw = 0; kw < 4; ++kw) {
                    float v = p[r * 4 + kw];
                    sn |= (u32)(v > 0.f) << kw;
                    nz |= (u32)(v != 0.f) << kw;
                }
                wpk21[tid * 8 + r] = sn | (nz << 8);
            }
        }
        {                 // 1x1 weights 256x64
            const float* p = w2_2 + (size_t)tid * 64;
            for (int j = 0; j < 2; ++j) {
                u32 sv = 0, nv = 0;
                for (int k = 0; k < 32; ++k) {
                    float v = p[j * 32 + k];
                    sv |= (u32)(v > 0.f) << k;
                    nv |= (u32)(v != 0.f) << k;
                }
                wp22[tid * 4 + j] = sv;
                wp22[tid * 4 + 2 + j] = nv;
            }
        }
        return;
    }
    {                     // blk == 13
        {                 // grouped 4x4 weights, C=256
            const float* p = w3_1 + tid * 32;
            for (int r = 0; r < 8; ++r) {
                u32 sn = 0, nz = 0;
                for (int kw = 0; kw < 4; ++kw) {
                    float v = p[r * 4 + kw];
                    sn |= (u32)(v > 0.f) << kw;
                    nz |= (u32)(v != 0.f) << kw;
                }
                wpk31[tid * 8 + r] = sn | (nz << 8);
            }
        }
        {                 // 1x1 weights 256x256
            const float* p = w3_2 + (size_t)tid * 256;
            for (int j = 0; j < 8; ++j) {
                u32 sv = 0, nv = 0;
                for (int k = 0; k < 32; ++k) {
                    float v = p[j * 32 + k];
                    sv |= (u32)(v > 0.f) << k;
                    nv |= (u32)(v != 0.f) << k;
                }
                wp32[tid * 16 + j] = sv;
                wp32[tid * 16 + 8 + j] = nv;
            }
        }
    }
}

// --- conv1 fused: block = (image, oc-group of 8); thread = 2x2 pool window ---
__global__ __launch_bounds__(256) void k_conv1f(const float* __restrict__ xpad,
                                                const float* __restrict__ swt,
                                                const float* __restrict__ g1,
                                                float* __restrict__ ppool,
                                                double* __restrict__ part)
{
    __shared__ float sacc_s[8 * 17];    // [j][16 s16-partials], pad 17
    __shared__ float sacc_q[8 * 17];
    int b = blockIdx.x >> 3, ocg = blockIdx.x & 7;
    int t = threadIdx.x;
    int lane = t & 63, wv = t >> 6;
    int oh = t >> 4, ow = t & 15;       // pooled position
    const float* xb = xpad + (size_t)b * 3780 + (2 * oh) * 36 + 2 * ow;
    float acc0[8], acc1[8], acc2[8], acc3[8];   // [pos(r,c)][oc j]
#pragma unroll
    for (int j = 0; j < 8; ++j) { acc0[j] = 0.f; acc1[j] = 0.f; acc2[j] = 0.f; acc3[j] = 0.f; }
#pragma unroll 1
    for (int ic = 0; ic < 3; ++ic) {
        const float* xr = xb + ic * 1260;
        const float* wic = swt + ic * 1024 + ocg * 8;
#pragma unroll
        for (int rr = 0; rr < 5; ++rr) {    // FULL unroll: batch loads for ILP
            float2 a01 = *(const float2*)xr;
            float2 a23 = *(const float2*)(xr + 2);
            float x0 = a01.x, x1 = a01.y, x2 = a23.x, x3 = a23.y, x4 = xr[4];
            if (rr <= 3) {              // out-row 2oh via kh=rr
                const float* wA = wic + rr * 256;
#pragma unroll
                for (int j = 0; j < 8; ++j) {
                    float w0 = wA[j], w1 = wA[64 + j], w2 = wA[128 + j], w3 = wA[192 + j];
                    acc0[j] = __builtin_fmaf(x0, w0, acc0[j]);
                    acc0[j] = __builtin_fmaf(x1, w1, acc0[j]);
                    acc0[j] = __builtin_fmaf(x2, w2, acc0[j]);
                    acc0[j] = __builtin_fmaf(x3, w3, acc0[j]);
                    acc1[j] = __builtin_fmaf(x1, w0, acc1[j]);
                    acc1[j] = __builtin_fmaf(x2, w1, acc1[j]);
                    acc1[j] = __builtin_fmaf(x3, w2, acc1[j]);
                    acc1[j] = __builtin_fmaf(x4, w3, acc1[j]);
                }
            }
            if (rr >= 1) {              // out-row 2oh+1 via kh=rr-1
                const float* wB = wic + (rr - 1) * 256;
#pragma unroll
                for (int j = 0; j < 8; ++j) {
                    float w0 = wB[j], w1 = wB[64 + j], w2 = wB[128 + j], w3 = wB[192 + j];
                    acc2[j] = __builtin_fmaf(x0, w0, acc2[j]);
                    acc2[j] = __builtin_fmaf(x1, w1, acc2[j]);
                    acc2[j] = __builtin_fmaf(x2, w2, acc2[j]);
                    acc2[j] = __builtin_fmaf(x3, w3, acc2[j]);
                    acc3[j] = __builtin_fmaf(x1, w0, acc3[j]);
                    acc3[j] = __builtin_fmaf(x2, w1, acc3[j]);
                    acc3[j] = __builtin_fmaf(x3, w2, acc3[j]);
                    acc3[j] = __builtin_fmaf(x4, w3, acc3[j]);
                }
            }
            xr += 36;
        }
    }
    bool owner16 = ((lane & 15) == 0);
    float* ppb = ppool + ((size_t)(b * 64 + ocg * 8)) * 256 + t;
#pragma unroll
    for (int j = 0; j < 8; ++j) {
        float a0 = acc0[j], a1 = acc1[j], a2 = acc2[j], a3 = acc3[j];
        bool posi = (g1[ocg * 8 + j] > 0.f);    // == sign(bn scale), uniform
        float pooled = posi ? fmaxf(fmaxf(a0, a1), fmaxf(a2, a3))
                            : fminf(fminf(a0, a1), fminf(a2, a3));
        float s = (a0 + a1) + (a2 + a3);
        float sq = a0 * a0 + a1 * a1 + a2 * a2 + a3 * a3;
        s += dppf<0xB1>(s);   sq += dppf<0xB1>(sq);
        s += dppf<0x4E>(s);   sq += dppf<0x4E>(sq);
        s += dppf<0x124>(s);  sq += dppf<0x124>(sq);
        s += dppf<0x128>(s);  sq += dppf<0x128>(sq);
        if (owner16) {
            int idx = j * 17 + wv * 4 + (lane >> 4);
            sacc_s[idx] = s;
            sacc_q[idx] = sq;
        }
        ppb[j * 256] = pooled;
    }
    __syncthreads();
    if (t < 16) {
        int j = t >> 1, half = t & 1;
        const float* sp = (half ? sacc_q : sacc_s) + j * 17;
        double acc = 0.0;
        for (int i = 0; i < 16; ++i) acc += (double)sp[i];
        part[(((size_t)(ocg * 8 + j)) * 512 + b) * 2 + half] = acc;
    }
}

// --- finalize: block per channel; mean/var -> power-of-two shift scale ---
__global__ __launch_bounds__(256) void k_finalize2(const double* __restrict__ part,
                                                   int nch, int N,
                                                   const float* __restrict__ gamma,
                                                   const float* __restrict__ beta,
                                                   float4* __restrict__ st)
{
    int c = blockIdx.x;
    double s = 0.0, sq = 0.0;
    for (int i = threadIdx.x; i < nch; i += 256) {
        s  += part[((size_t)c * nch + i) * 2];
        sq += part[((size_t)c * nch + i) * 2 + 1];
    }
    __shared__ double ss[256];
    __shared__ double sb[256];
    ss[threadIdx.x] = s; sb[threadIdx.x] = sq;
    __syncthreads();
    for (int stp = 128; stp > 0; stp >>= 1) {
        if (threadIdx.x < stp) {
            ss[threadIdx.x] += ss[threadIdx.x + stp];
            sb[threadIdx.x] += sb[threadIdx.x + stp];
        }
        __syncthreads();
    }
    if (threadIdx.x == 0) {
        double mean = ss[0] / (double)N;
        double var = sb[0] / (double)N - mean * mean;
        float inv = gamma[c] / sqrtf((float)var + 1e-5f);
        float sh = rintf(log2f(fabsf(inv) + 1e-12f));
        sh = fminf(fmaxf(sh, -4.f), 4.f);
        float scale = copysignf(exp2f(sh), inv);
        st[c] = make_float4((float)mean, scale, beta[c], 0.f);
    }
}

// --- merged stats+finalize, int8 tensor [512][256][256] per channel ---
__global__ __launch_bounds__(1024) void k_statsfin8(const signed char* __restrict__ in,
                                                    const float* __restrict__ gamma,
                                                    const float* __restrict__ beta,
                                                    float4* __restrict__ st)
{
    int c = blockIdx.x;
    int s = 0, sq = 0;
    for (int i = threadIdx.x; i < 32768; i += 1024) {   // 512 b x 64 words
        int b = i >> 6, w = i & 63;
        u32 v = ((const u32*)in)[((size_t)(b * 256 + c) << 6) + w];
        int x0 = (int)(v << 24) >> 24, x1 = (int)(v << 16) >> 24;
        int x2 = (int)(v << 8) >> 24,  x3 = (int)v >> 24;
        s += x0 + x1 + x2 + x3;
        sq += x0 * x0 + x1 * x1 + x2 * x2 + x3 * x3;
    }
    __shared__ int ss[1024];
    __shared__ int sb[1024];
    ss[threadIdx.x] = s; sb[threadIdx.x] = sq;
    __syncthreads();
    for (int stp = 512; stp > 0; stp >>= 1) {
        if (threadIdx.x < stp) {
            ss[threadIdx.x] += ss[threadIdx.x + stp];
            sb[threadIdx.x] += sb[threadIdx.x + stp];
        }
        __syncthreads();
    }
    if (threadIdx.x == 0) {
        double mean = (double)ss[0] / 131072.0;
        double var = (double)sb[0] / 131072.0 - mean * mean;
        float inv = gamma[c] / sqrtf((float)var + 1e-5f);
        float sh = rintf(log2f(fabsf(inv) + 1e-12f));
        sh = fminf(fmaxf(sh, -4.f), 4.f);
        float scale = copysignf(exp2f(sh), inv);
        st[c] = make_float4((float)mean, scale, beta[c], 0.f);
    }
}

// --- merged stats+finalize, int16 tensor [512][256][64] per channel ---
__global__ __launch_bounds__(1024) void k_statsfin16(const short* __restrict__ in,
                                                     const float* __restrict__ gamma,
                                                     const float* __restrict__ beta,
                                                     float4* __restrict__ st)
{
    int c = blockIdx.x;
    int s = 0, sq = 0;
    for (int i = threadIdx.x; i < 16384; i += 1024) {   // 512 b x 32 words
        int b = i >> 5, w = i & 31;
        u32 v = ((const u32*)in)[((size_t)(b * 256 + c) << 5) + w];
        int x0 = (int)(v << 16) >> 16, x1 = (int)v >> 16;
        s += x0 + x1;
        sq += x0 * x0 + x1 * x1;
    }
    __shared__ double ss[1024];
    __shared__ double sb[1024];
    ss[threadIdx.x] = (double)s; sb[threadIdx.x] = (double)sq;
    __syncthreads();
    for (int stp = 512; stp > 0; stp >>= 1) {
        if (threadIdx.x < stp) {
            ss[threadIdx.x] += ss[threadIdx.x + stp];
            sb[threadIdx.x] += sb[threadIdx.x + stp];
        }
        __syncthreads();
    }
    if (threadIdx.x == 0) {
        double mean = ss[0] / 32768.0;
        double var = sb[0] / 32768.0 - mean * mean;
        float inv = gamma[c] / sqrtf((float)var + 1e-5f);
        float sh = rintf(log2f(fabsf(inv) + 1e-12f));
        sh = fminf(fmaxf(sh, -4.f), 4.f);
        float scale = copysignf(exp2f(sh), inv);
        st[c] = make_float4((float)mean, scale, beta[c], 0.f);
    }
}

// --- FUSED layer-2 head: block = (image, channel-half of 32). 256 thr. ---
__global__ __launch_bounds__(256) void k_fuse2(const float* __restrict__ ppool,
                                               const float4* __restrict__ st,
                                               const u32* __restrict__ wpk,
                                               signed char* __restrict__ out,
                                               double* __restrict__ part)
{
    __shared__ u32 lspk[32 * 20];
    __shared__ u32 lnpk[32 * 20];
    int b = blockIdx.x >> 1, half = blockIdx.x & 1;
    int t = threadIdx.x;
    // phase 1: bn + binarize + row-pack, 32 ch x 16 rows (2 items/thread)
#pragma unroll
    for (int k = 0; k < 2; ++k) {
        int e = t + k * 256;
        int cl = e >> 4, oh = e & 15;
        int c = half * 32 + cl;
        float4 s = st[c];
        const float4* p = (const float4*)(ppool + ((size_t)(b * 64 + c)) * 256 + oh * 16);
        u32 sb = 0, nb = 0;
#pragma unroll
        for (int j = 0; j < 4; ++j) {
            float4 v4 = p[j];
            float vs[4] = {v4.x, v4.y, v4.z, v4.w};
#pragma unroll
            for (int kk = 0; kk < 4; ++kk) {
                float v = (vs[kk] - s.x) * s.y + s.z;
                int ow = j * 4 + kk;
                sb |= (u32)(v > 0.f) << (ow + 1);
                nb |= (u32)(v != 0.f) << (ow + 1);
            }
        }
        lspk[cl * 20 + 1 + oh] = sb;
        lnpk[cl * 20 + 1 + oh] = nb;
        if (oh < 4) {
            int zs = (oh == 0) ? 0 : (16 + oh);
            lspk[cl * 20 + zs] = 0; lnpk[cl * 20 + zs] = 0;
        }
    }
    __syncthreads();
    // phase 2: grouped conv, 16 groups x 16 rows (1 item/thread)
    int gl = t >> 4, h = t & 15;
    int g = half * 16 + gl;
    const u32* sp = lspk + (2 * gl) * 20 + h;
    const u32* np = lnpk + (2 * gl) * 20 + h;
    u32 S[8], N[8];
#pragma unroll
    for (int jc = 0; jc < 2; ++jc)
#pragma unroll
        for (int jj = 0; jj < 4; ++jj) {
            S[jc * 4 + jj] = sp[jc * 20 + jj];
            N[jc * 4 + jj] = np[jc * 20 + jj];
        }
    const u32* wq = wpk + (size_t)(2 * g) * 8;
    u32 Ws0[8], Wn0[8], Ws1[8], Wn1[8];
#pragma unroll
    for (int r = 0; r < 8; ++r) {
        u32 a = wq[r];      Ws0[r] = a & 15u;  Wn0[r] = (a >> 8) & 15u;
        u32 bb = wq[8 + r]; Ws1[r] = bb & 15u; Wn1[r] = (bb >> 8) & 15u;
    }
    int v0[16], v1[16];
    int s0 = 0, q0 = 0, s1 = 0, q1 = 0;
#pragma unroll
    for (int w = 0; w < 16; ++w) {
        int snz0 = 0, smis0 = 0, snz1 = 0, smis1 = 0;
#pragma unroll
        for (int r = 0; r < 8; ++r) {
            u32 ss = (S[r] >> w) & 15u;
            u32 nn = (N[r] >> w) & 15u;
            u32 nz0 = nn & Wn0[r]; u32 m0 = (ss ^ Ws0[r]) & nz0;
            snz0 += __popc(nz0); smis0 += __popc(m0);
            u32 nz1 = nn & Wn1[r]; u32 m1 = (ss ^ Ws1[r]) & nz1;
            snz1 += __popc(nz1); smis1 += __popc(m1);
        }
        v0[w] = snz0 - 2 * smis0;
        v1[w] = snz1 - 2 * smis1;
        s0 += v0[w]; q0 += v0[w] * v0[w];
        s1 += v1[w]; q1 += v1[w] * v1[w];
    }
#pragma unroll
    for (int m = 1; m < 16; m <<= 1) {
        s0 += __shfl_xor(s0, m); q0 += __shfl_xor(q0, m);
        s1 += __shfl_xor(s1, m); q1 += __shfl_xor(q1, m);
    }
    if (h == 0) {
        part[((size_t)(2 * g) * 512 + b) * 2]         = (double)s0;
        part[((size_t)(2 * g) * 512 + b) * 2 + 1]     = (double)q0;
        part[((size_t)(2 * g + 1) * 512 + b) * 2]     = (double)s1;
        part[((size_t)(2 * g + 1) * 512 + b) * 2 + 1] = (double)q1;
    }
    signed char* o0 = out + ((size_t)((b * 64 + 2 * g) * 16 + h)) * 16;
    signed char* o1 = o0 + 256;
    u32 wb0[4], wb1[4];
#pragma unroll
    for (int j = 0; j < 4; ++j) {
        wb0[j] = pack4(v0[4*j], v0[4*j+1], v0[4*j+2], v0[4*j+3]);
        wb1[j] = pack4(v1[4*j], v1[4*j+1], v1[4*j+2], v1[4*j+3]);
    }
    *(uint4*)o0 = make_uint4(wb0[0], wb0[1], wb0[2], wb0[3]);
    *(uint4*)o1 = make_uint4(wb1[0], wb1[1], wb1[2], wb1[3]);
}

// --- 1x1 conv Cin=64->Cout=256 (oc halves), HW=256, FUSED bn binarize+pack ---
__global__ __launch_bounds__(256) void k_conv1x1_bp2(const signed char* __restrict__ q8,
                                                     const float4* __restrict__ st,
                                                     const u32* __restrict__ wp,
                                                     signed char* __restrict__ out)
{
    int b = blockIdx.x >> 1, hoc = blockIdx.x & 1;
    int hw = threadIdx.x;
    const signed char* qp = q8 + (size_t)b * 64 * 256 + hw;
    u32 as0 = 0, as1 = 0, an0 = 0, an1 = 0;
#pragma unroll
    for (int k = 0; k < 32; ++k) {
        float4 s = st[k];                       // uniform -> s_load
        float v = ((float)qp[k * 256] - s.x) * s.y + s.z;   // coalesced byte load
        as0 |= (u32)(v > 0.f) << k;
        an0 |= (u32)(v != 0.f) << k;
    }
#pragma unroll
    for (int k = 0; k < 32; ++k) {
        float4 s = st[32 + k];
        float v = ((float)qp[(32 + k) * 256] - s.x) * s.y + s.z;
        as1 |= (u32)(v > 0.f) << k;
        an1 |= (u32)(v != 0.f) << k;
    }
    signed char* op = out + (size_t)b * 256 * 256 + hw;
    int oc0 = hoc * 128;
#pragma unroll 8
    for (int oc = oc0; oc < oc0 + 128; ++oc) {
        uint4 wv = ((const uint4*)wp)[oc];      // wave-uniform -> scalar loads
        u32 nz0 = an0 & wv.z, nz1 = an1 & wv.w;
        u32 m0 = (as0 ^ wv.x) & nz0, m1 = (as1 ^ wv.y) & nz1;
        int dot = __popc(nz0) + __popc(nz1) - 2 * (__popc(m0) + __popc(m1));
        op[(size_t)oc << 8] = (signed char)dot;
    }
}

// --- FUSED layer-3 head: block = (image, quarter of 64 ch / 32 groups). ---
__global__ __launch_bounds__(256) void k_fuse3(const signed char* __restrict__ c22,
                                               const float4* __restrict__ st,
                                               const u32* __restrict__ wpk,
                                               signed char* __restrict__ out,
                                               double* __restrict__ part)
{
    __shared__ u32 lspk[64 * 12];
    __shared__ u32 lnpk[64 * 12];
    int b = blockIdx.x >> 2, qd = blockIdx.x & 3;
    int t = threadIdx.x;
    // phase 1: bn+pool+binarize+pack, 64 ch x 8 rows (2 items/thread)
#pragma unroll
    for (int k = 0; k < 2; ++k) {
        int e = t + k * 256;
        int cl = e >> 3, oh = e & 7;
        int c = qd * 64 + cl;
        float4 s = st[c];
        const uint4* p = (const uint4*)(c22 + ((size_t)(b * 256 + c)) * 256 + (size_t)(2 * oh) * 16);
        uint4 r0 = p[0], r1 = p[1];
        bool pos = (s.y > 0.f);
        u32 rows0[4] = {r0.x, r0.y, r0.z, r0.w};
        u32 rows1[4] = {r1.x, r1.y, r1.z, r1.w};
        u32 sb = 0, nb = 0;
#pragma unroll
        for (int j = 0; j < 4; ++j) {
            u32 a = rows0[j], bw = rows1[j];
#pragma unroll
            for (int kk = 0; kk < 2; ++kk) {
                int sh0 = 24 - 16 * kk, sh1 = 16 - 16 * kk;
                int a0 = (int)(a  << sh0) >> 24, a1 = (int)(a  << sh1) >> 24;
                int a2 = (int)(bw << sh0) >> 24, a3 = (int)(bw << sh1) >> 24;
                int raw = pos ? max(max(a0, a1), max(a2, a3))
                              : min(min(a0, a1), min(a2, a3));
                float v = ((float)raw - s.x) * s.y + s.z;
                int ow = j * 2 + kk;
                sb |= (u32)(v > 0.f) << (ow + 1);
                nb |= (u32)(v != 0.f) << (ow + 1);
            }
        }
        lspk[cl * 12 + 1 + oh] = sb;
        lnpk[cl * 12 + 1 + oh] = nb;
        if (oh < 4) {
            int zs = (oh == 0) ? 0 : (8 + oh);
            lspk[cl * 12 + zs] = 0; lnpk[cl * 12 + zs] = 0;
        }
    }
    __syncthreads();
    // phase 2: grouped conv, 32 groups x 8 rows (1 item/thread)
    int gl = t >> 3, h = t & 7;
    int g = qd * 32 + gl;
    const u32* sp = lspk + (2 * gl) * 12 + h;
    const u32* np = lnpk + (2 * gl) * 12 + h;
    u32 S[8], N[8];
#pragma unroll
    for (int jc = 0; jc < 2; ++jc)
#pragma unroll
        for (int jj = 0; jj < 4; ++jj) {
            S[jc * 4 + jj] = sp[jc * 12 + jj];
            N[jc * 4 + jj] = np[jc * 12 + jj];
        }
    const u32* wq = wpk + (size_t)(2 * g) * 8;
    u32 Ws0[8], Wn0[8], Ws1[8], Wn1[8];
#pragma unroll
    for (int r = 0; r < 8; ++r) {
        u32 a = wq[r];      Ws0[r] = a & 15u;  Wn0[r] = (a >> 8) & 15u;
        u32 bb = wq[8 + r]; Ws1[r] = bb & 15u; Wn1[r] = (bb >> 8) & 15u;
    }
    int v0[8], v1[8];
    int s0 = 0, q0 = 0, s1 = 0, q1 = 0;
#pragma unroll
    for (int w = 0; w < 8; ++w) {
        int snz0 = 0, smis0 = 0, snz1 = 0, smis1 = 0;
#pragma unroll
        for (int r = 0; r < 8; ++r) {
            u32 ss = (S[r] >> w) & 15u;
            u32 nn = (N[r] >> w) & 15u;
            u32 nz0 = nn & Wn0[r]; u32 m0 = (ss ^ Ws0[r]) & nz0;
            snz0 += __popc(nz0); smis0 += __popc(m0);
            u32 nz1 = nn & Wn1[r]; u32 m1 = (ss ^ Ws1[r]) & nz1;
            snz1 += __popc(nz1); smis1 += __popc(m1);
        }
        v0[w] = snz0 - 2 * smis0;
        v1[w] = snz1 - 2 * smis1;
        s0 += v0[w]; q0 += v0[w] * v0[w];
        s1 += v1[w]; q1 += v1[w] * v1[w];
    }
#pragma unroll
    for (int m = 1; m < 8; m <<= 1) {
        s0 += __shfl_xor(s0, m); q0 += __shfl_xor(q0, m);
        s1 += __shfl_xor(s1, m); q1 += __shfl_xor(q1, m);
    }
    if (h == 0) {
        part[((size_t)(2 * g) * 512 + b) * 2]         = (double)s0;
        part[((size_t)(2 * g) * 512 + b) * 2 + 1]     = (double)q0;
        part[((size_t)(2 * g + 1) * 512 + b) * 2]     = (double)s1;
        part[((size_t)(2 * g + 1) * 512 + b) * 2 + 1] = (double)q1;
    }
    signed char* o0 = out + ((size_t)((b * 256 + 2 * g) * 8 + h)) * 8;
    signed char* o1 = o0 + 64;
    *(uint2*)o0 = make_uint2(pack4(v0[0], v0[1], v0[2], v0[3]),
                             pack4(v0[4], v0[5], v0[6], v0[7]));
    *(uint2*)o1 = make_uint2(pack4(v1[0], v1[1], v1[2], v1[3]),
                             pack4(v1[4], v1[5], v1[6], v1[7]));
}

// --- FUSED: bn+binarize+channel-pack (LDS) -> 1x1 conv Cin=256, int16 out ---
__global__ __launch_bounds__(256) void k_fuse4(const signed char* __restrict__ q8,
                                               const float4* __restrict__ st,
                                               const u32* __restrict__ wp,
                                               short* __restrict__ out)
{
    __shared__ u32 sq[4096];       // one image: 256ch x 64hw bytes
    __shared__ u32 act[64 * 17];   // [hw][16 words], pad 17
    int b = blockIdx.x, t = threadIdx.x;
    const u32* qb = (const u32*)(q8 + (size_t)b * 16384);
    for (int i = t; i < 4096; i += 256) sq[i] = qb[i];
    __syncthreads();
    {
        const signed char* s8p = (const signed char*)sq;
        int hw = t & 63, qd = t >> 6;
        u32 sv0 = 0, nv0 = 0, sv1 = 0, nv1 = 0;
#pragma unroll
        for (int k = 0; k < 32; ++k) {
            int c = qd * 64 + k;
            float4 s = st[c];
            float v = ((float)s8p[c * 64 + hw] - s.x) * s.y + s.z;
            sv0 |= (u32)(v > 0.f) << k;
            nv0 |= (u32)(v != 0.f) << k;
        }
#pragma unroll
        for (int k = 0; k < 32; ++k) {
            int c = qd * 64 + 32 + k;
            float4 s = st[c];
            float v = ((float)s8p[c * 64 + hw] - s.x) * s.y + s.z;
            sv1 |= (u32)(v > 0.f) << k;
            nv1 |= (u32)(v != 0.f) << k;
        }
        u32* ap = act + hw * 17;
        ap[qd * 2]     = sv0;
        ap[qd * 2 + 1] = sv1;
        ap[8 + qd * 2]     = nv0;
        ap[8 + qd * 2 + 1] = nv1;
    }
    __syncthreads();
    int hw = t & 63, ch = t >> 6;
    const u32* ap = act + hw * 17;
    u32 as[8], an[8];
#pragma unroll
    for (int j = 0; j < 8; ++j) { as[j] = ap[j]; an[j] = ap[8 + j]; }
    short* op = out + (size_t)b * 256 * 64 + hw;
#pragma unroll 4
    for (int oc = ch * 64; oc < ch * 64 + 64; ++oc) {
        const u32* wq = wp + oc * 16;
        int snz = 0, smis = 0;
#pragma unroll
        for (int j = 0; j < 8; ++j) {
            u32 nz = an[j] & wq[8 + j];
            u32 m = (as[j] ^ wq[j]) & nz;
            snz += __popc(nz); smis += __popc(m);
        }
        op[(size_t)oc * 64] = (short)(snz - 2 * smis);
    }
}

// --- FC: block per image (512 thr), bn3_2 inline, features read once ---
__global__ __launch_bounds__(512) void k_fc2(const short* __restrict__ f,
                                             const float4* __restrict__ st,
                                             const float* __restrict__ fcw,
                                             const float* __restrict__ fcb,
                                             float* __restrict__ out)
{
    int b = blockIdx.x, t = threadIdx.x;
    int lane = t & 63, wv = t >> 6;
    const u32* fp = (const u32*)(f + (size_t)b * 16384);
    float acc[10];
#pragma unroll
    for (int n = 0; n < 10; ++n) acc[n] = 0.f;
    for (int i = 0; i < 16; ++i) {
        int j = i * 512 + t;                 // u32 index; features 2j, 2j+1
        u32 v = fp[j];
        float4 s = st[j >> 5];               // channel = (2j)>>6 = j>>5
        float f0 = ((float)((int)(v << 16) >> 16) - s.x) * s.y + s.z;
        float f1 = ((float)((int)v >> 16) - s.x) * s.y + s.z;
#pragma unroll
        for (int n = 0; n < 10; ++n) {
            float2 wv2 = *(const float2*)(fcw + (size_t)n * 16384 + 2 * j);
            acc[n] += f0 * wv2.x + f1 * wv2.y;
        }
    }
#pragma unroll
    for (int n = 0; n < 10; ++n)
#pragma unroll
        for (int m = 1; m < 64; m <<= 1) acc[n] += __shfl_xor(acc[n], m);
    __shared__ float sred[8][10];
    if (lane == 0)
#pragma unroll
        for (int n = 0; n < 10; ++n) sred[wv][n] = acc[n];
    __syncthreads();
    if (t < 10) {
        float r = fcb[t];
#pragma unroll
        for (int w = 0; w < 8; ++w) r += sred[w][t];
        out[b * 10 + t] = r;
    }
}

extern "C" void kernel_launch(void* const* d_in, const int* in_sizes, int n_in,
                              void* d_out, int out_size, void* d_ws, size_t ws_size,
                              hipStream_t stream)
{
    const float* x    = (const float*)d_in[0];
    const float* w1   = (const float*)d_in[1];
    const float* g1   = (const float*)d_in[2];
    const float* b1   = (const float*)d_in[3];
    const float* w2_1 = (const float*)d_in[4];
    const float* g2_1 = (const float*)d_in[5];
    const float* b2_1 = (const float*)d_in[6];
    const float* w2_2 = (const float*)d_in[7];
    const float* g2_2 = (const float*)d_in[8];
    const float* b2_2 = (const float*)d_in[9];
    const float* w3_1 = (const float*)d_in[10];
    const float* g3_1 = (const float*)d_in[11];
    const float* b3_1 = (const float*)d_in[12];
    const float* w3_2 = (const float*)d_in[13];
    const float* g3_2 = (const float*)d_in[14];
    const float* b3_2 = (const float*)d_in[15];
    const float* fcw  = (const float*)d_in[16];
    const float* fcb  = (const float*)d_in[17];
    float* out = (float*)d_out;

    // workspace layout (bytes). ppool aliases later c22 (write-after-consume
    // ordering per launch sequence).
    const size_t OFF_PPOOL= 0;          // 33,554,432  (-> c22 later)
    const size_t OFF_F3   = 33554432;   // 16,777,216  conv3_2 int16 out
    const size_t OFF_Q    = 50331648;   //  8,388,608  convg int8 outs
    const size_t OFF_WPK21= 67108864;   //  2,048
    const size_t OFF_WPK31= 67110912;   //  8,192
    const size_t OFF_WP22 = 67119104;   //  4,096
    const size_t OFF_WP32 = 67123200;   //  16,384
    const size_t OFF_PART = 67139584;   //  2,097,152
    const size_t OFF_ST   = 69236736;   //  20,480     5 x 256 float4
    const size_t OFF_SWT  = 69257216;   //  12,288     conv1 signed weights, tap-major f32
    const size_t OFF_XPAD = 69269504;   //  7,741,440  padded input [512*3][35][36]
    const size_t NEED     = OFF_XPAD + 7741440;
    if (ws_size < NEED) return;

    char* ws = (char*)d_ws;
    float* ppool = (float*)(ws + OFF_PPOOL);
    signed char* c22 = (signed char*)(ws + OFF_PPOOL); // after k_fuse2 consumes ppool
    short* f3  = (short*)(ws + OFF_F3);
    signed char* q8 = (signed char*)(ws + OFF_Q);
    u32* wpk21 = (u32*)(ws + OFF_WPK21);
    u32* wpk31 = (u32*)(ws + OFF_WPK31);
    u32* wp22  = (u32*)(ws + OFF_WP22);
    u32* wp32  = (u32*)(ws + OFF_WP32);
    double* part = (double*)(ws + OFF_PART);
    float4* st1  = (float4*)(ws + OFF_ST);
    float4* st21 = st1 + 256;
    float4* st22 = st21 + 256;
    float4* st31 = st22 + 256;
    float4* st32 = st31 + 256;
    float* swt   = (float*)(ws + OFF_SWT);
    float* xpad  = (float*)(ws + OFF_XPAD);

    // ---- weight prep + input pad (one launch) ----
    k_wprep<<<7574, 256, 0, stream>>>(w1, swt, w2_1, wpk21, w3_1, wpk31,
                                      w2_2, wp22, w3_2, wp32, x, xpad);

    // ---- layer 1 ----
    k_conv1f<<<4096, 256, 0, stream>>>(xpad, swt, g1, ppool, part);
    k_finalize2<<<64, 256, 0, stream>>>(part, 512, 512 * 1024, g1, b1, st1);

    // ---- layer 2 (pack+gconv fused, channel-split) ----
    k_fuse2<<<1024, 256, 0, stream>>>(ppool, st1, wpk21, q8, part);
    k_finalize2<<<64, 256, 0, stream>>>(part, 512, 512 * 256, g2_1, b2_1, st21);
    k_conv1x1_bp2<<<1024, 256, 0, stream>>>(q8, st21, wp22, c22);
    k_statsfin8<<<256, 1024, 0, stream>>>(c22, g2_2, b2_2, st22);

    // ---- layer 3 (pool+pack+gconv fused, quarter-split; pack+1x1 fused) ----
    k_fuse3<<<2048, 256, 0, stream>>>(c22, st22, wpk31, q8, part);
    k_finalize2<<<256, 256, 0, stream>>>(part, 512, 512 * 64, g3_1, b3_1, st31);
    k_fuse4<<<512, 256, 0, stream>>>(q8, st31, wp32, f3);
    k_statsfin16<<<256, 1024, 0, stream>>>(f3, g3_2, b3_2, st32);

    // ---- FC (bn3_2 inline) ----
    k_fc2<<<512, 512, 0, stream>>>(f3, st32, fcw, fcb, out);
}

// Round 19
// 186.808 us; speedup vs baseline: 1.7702x; 1.0277x over previous
//
#include <hip/hip_runtime.h>

typedef unsigned int u32;

// ---------------------------------------------------------------------------
// LiBNet forward, bit-packed ternary arithmetic + integer intermediates.
// dot over taps = popc(nzA & nzW) - 2*popc((sA ^ sW) & nzA & nzW)
// conv1: thread = 2x2 pooled window x 8 oc, fmaf chains, rr loop fully
// unrolled. Global/L2 padded input (LDS staging measured worse). Mid
// kernels channel-split for TLP. FC: 2 images/block to halve fcw traffic.
// ---------------------------------------------------------------------------

static __device__ __forceinline__ float fsign(float x) {
    return (x > 0.f) ? 1.f : ((x < 0.f) ? -1.f : 0.f);
}
static __device__ __forceinline__ u32 pack4(int a, int b, int c, int d) {
    return (a & 0xff) | ((b & 0xff) << 8) | ((c & 0xff) << 16) | ((u32)(d & 0xff) << 24);
}
// DPP on float (VALU pipe). 0xB1 = quad lane^1, 0x4E = quad lane^2,
// 0x124 = row_ror:4, 0x128 = row_ror:8 (16-lane row rotations).
template <int CTRL>
static __device__ __forceinline__ float dppf(float x) {
    int i = __builtin_amdgcn_mov_dpp(__float_as_int(x), CTRL, 0xF, 0xF, true);
    return __int_as_float(i);
}

// --- weight prep + input padding (one launch) ---
__global__ __launch_bounds__(256) void k_wprep(const float* __restrict__ w1, float* __restrict__ swt,
                                               const float* __restrict__ w2_1, u32* __restrict__ wpk21,
                                               const float* __restrict__ w3_1, u32* __restrict__ wpk31,
                                               const float* __restrict__ w2_2, u32* __restrict__ wp22,
                                               const float* __restrict__ w3_2, u32* __restrict__ wp32,
                                               const float* __restrict__ x, float* __restrict__ xpad)
{
    int blk = blockIdx.x, tid = threadIdx.x;
    if (blk >= 14) {                    // pad x -> xpad [512*3][35][36]
        int i = (blk - 14) * 256 + tid;
        if (i < 1935360) {
            int bic = i / 1260;
            int rem = i - bic * 1260;
            int r = rem / 36, c = rem - r * 36;
            float v = 0.f;
            if (r >= 1 && r <= 32 && c >= 1 && c <= 32)
                v = x[bic * 1024 + (r - 1) * 32 + (c - 1)];
            xpad[i] = v;
        }
        return;
    }
    if (blk < 12) {
        int i = blk * 256 + tid;
        if (i < 3072) {
            int k = i >> 6, oc = i & 63;
            swt[i] = fsign(w1[oc * 48 + k]);   // tap-major
        }
        return;
    }
    if (blk == 12) {
        if (tid < 64) {   // grouped 4x4 weights, C=64
            const float* p = w2_1 + tid * 32;
            for (int r = 0; r < 8; ++r) {
                u32 sn = 0, nz = 0;
                for (int kw = 0; kw < 4; ++kw) {
                    float v = p[r * 4 + kw];
                    sn |= (u32)(v > 0.f) << kw;
                    nz |= (u32)(v != 0.f) << kw;
                }
                wpk21[tid * 8 + r] = sn | (nz << 8);
            }
        }
        {                 // 1x1 weights 256x64
            const float* p = w2_2 + (size_t)tid * 64;
            for (int j = 0; j < 2; ++j) {
                u32 sv = 0, nv = 0;
                for (int k = 0; k < 32; ++k) {
                    float v = p[j * 32 + k];
                    sv |= (u32)(v > 0.f) << k;
                    nv |= (u32)(v != 0.f) << k;
                }
                wp22[tid * 4 + j] = sv;
                wp22[tid * 4 + 2 + j] = nv;
            }
        }
        return;
    }
    {                     // blk == 13
        {                 // grouped 4x4 weights, C=256
            const float* p = w3_1 + tid * 32;
            for (int r = 0; r < 8; ++r) {
                u32 sn = 0, nz = 0;
                for (int kw = 0; kw < 4; ++kw) {
                    float v = p[r * 4 + kw];
                    sn |= (u32)(v > 0.f) << kw;
                    nz |= (u32)(v != 0.f) << kw;
                }
                wpk31[tid * 8 + r] = sn | (nz << 8);
            }
        }
        {                 // 1x1 weights 256x256
            const float* p = w3_2 + (size_t)tid * 256;
            for (int j = 0; j < 8; ++j) {
                u32 sv = 0, nv = 0;
                for (int k = 0; k < 32; ++k) {
                    float v = p[j * 32 + k];
                    sv |= (u32)(v > 0.f) << k;
                    nv |= (u32)(v != 0.f) << k;
                }
                wp32[tid * 16 + j] = sv;
                wp32[tid * 16 + 8 + j] = nv;
            }
        }
    }
}

// --- conv1 fused: block = (image, oc-group of 8); thread = 2x2 pool window ---
__global__ __launch_bounds__(256) void k_conv1f(const float* __restrict__ xpad,
                                                const float* __restrict__ swt,
                                                const float* __restrict__ g1,
                                                float* __restrict__ ppool,
                                                double* __restrict__ part)
{
    __shared__ float sacc_s[8 * 17];    // [j][16 s16-partials], pad 17
    __shared__ float sacc_q[8 * 17];
    int b = blockIdx.x >> 3, ocg = blockIdx.x & 7;
    int t = threadIdx.x;
    int lane = t & 63, wv = t >> 6;
    int oh = t >> 4, ow = t & 15;       // pooled position
    const float* xb = xpad + (size_t)b * 3780 + (2 * oh) * 36 + 2 * ow;
    float acc0[8], acc1[8], acc2[8], acc3[8];   // [pos(r,c)][oc j]
#pragma unroll
    for (int j = 0; j < 8; ++j) { acc0[j] = 0.f; acc1[j] = 0.f; acc2[j] = 0.f; acc3[j] = 0.f; }
#pragma unroll 1
    for (int ic = 0; ic < 3; ++ic) {
        const float* xr = xb + ic * 1260;
        const float* wic = swt + ic * 1024 + ocg * 8;
#pragma unroll
        for (int rr = 0; rr < 5; ++rr) {    // FULL unroll: batch loads for ILP
            float2 a01 = *(const float2*)xr;
            float2 a23 = *(const float2*)(xr + 2);
            float x0 = a01.x, x1 = a01.y, x2 = a23.x, x3 = a23.y, x4 = xr[4];
            if (rr <= 3) {              // out-row 2oh via kh=rr
                const float* wA = wic + rr * 256;
#pragma unroll
                for (int j = 0; j < 8; ++j) {
                    float w0 = wA[j], w1 = wA[64 + j], w2 = wA[128 + j], w3 = wA[192 + j];
                    acc0[j] = __builtin_fmaf(x0, w0, acc0[j]);
                    acc0[j] = __builtin_fmaf(x1, w1, acc0[j]);
                    acc0[j] = __builtin_fmaf(x2, w2, acc0[j]);
                    acc0[j] = __builtin_fmaf(x3, w3, acc0[j]);
                    acc1[j] = __builtin_fmaf(x1, w0, acc1[j]);
                    acc1[j] = __builtin_fmaf(x2, w1, acc1[j]);
                    acc1[j] = __builtin_fmaf(x3, w2, acc1[j]);
                    acc1[j] = __builtin_fmaf(x4, w3, acc1[j]);
                }
            }
            if (rr >= 1) {              // out-row 2oh+1 via kh=rr-1
                const float* wB = wic + (rr - 1) * 256;
#pragma unroll
                for (int j = 0; j < 8; ++j) {
                    float w0 = wB[j], w1 = wB[64 + j], w2 = wB[128 + j], w3 = wB[192 + j];
                    acc2[j] = __builtin_fmaf(x0, w0, acc2[j]);
                    acc2[j] = __builtin_fmaf(x1, w1, acc2[j]);
                    acc2[j] = __builtin_fmaf(x2, w2, acc2[j]);
                    acc2[j] = __builtin_fmaf(x3, w3, acc2[j]);
                    acc3[j] = __builtin_fmaf(x1, w0, acc3[j]);
                    acc3[j] = __builtin_fmaf(x2, w1, acc3[j]);
                    acc3[j] = __builtin_fmaf(x3, w2, acc3[j]);
                    acc3[j] = __builtin_fmaf(x4, w3, acc3[j]);
                }
            }
            xr += 36;
        }
    }
    bool owner16 = ((lane & 15) == 0);
    float* ppb = ppool + ((size_t)(b * 64 + ocg * 8)) * 256 + t;
#pragma unroll
    for (int j = 0; j < 8; ++j) {
        float a0 = acc0[j], a1 = acc1[j], a2 = acc2[j], a3 = acc3[j];
        bool posi = (g1[ocg * 8 + j] > 0.f);    // == sign(bn scale), uniform
        float pooled = posi ? fmaxf(fmaxf(a0, a1), fmaxf(a2, a3))
                            : fminf(fminf(a0, a1), fminf(a2, a3));
        float s = (a0 + a1) + (a2 + a3);
        float sq = a0 * a0 + a1 * a1 + a2 * a2 + a3 * a3;
        s += dppf<0xB1>(s);   sq += dppf<0xB1>(sq);
        s += dppf<0x4E>(s);   sq += dppf<0x4E>(sq);
        s += dppf<0x124>(s);  sq += dppf<0x124>(sq);
        s += dppf<0x128>(s);  sq += dppf<0x128>(sq);
        if (owner16) {
            int idx = j * 17 + wv * 4 + (lane >> 4);
            sacc_s[idx] = s;
            sacc_q[idx] = sq;
        }
        ppb[j * 256] = pooled;
    }
    __syncthreads();
    if (t < 16) {
        int j = t >> 1, half = t & 1;
        const float* sp = (half ? sacc_q : sacc_s) + j * 17;
        double acc = 0.0;
        for (int i = 0; i < 16; ++i) acc += (double)sp[i];
        part[(((size_t)(ocg * 8 + j)) * 512 + b) * 2 + half] = acc;
    }
}

// --- finalize: block per channel; mean/var -> power-of-two shift scale ---
__global__ __launch_bounds__(256) void k_finalize2(const double* __restrict__ part,
                                                   int nch, int N,
                                                   const float* __restrict__ gamma,
                                                   const float* __restrict__ beta,
                                                   float4* __restrict__ st)
{
    int c = blockIdx.x;
    double s = 0.0, sq = 0.0;
    for (int i = threadIdx.x; i < nch; i += 256) {
        s  += part[((size_t)c * nch + i) * 2];
        sq += part[((size_t)c * nch + i) * 2 + 1];
    }
    __shared__ double ss[256];
    __shared__ double sb[256];
    ss[threadIdx.x] = s; sb[threadIdx.x] = sq;
    __syncthreads();
    for (int stp = 128; stp > 0; stp >>= 1) {
        if (threadIdx.x < stp) {
            ss[threadIdx.x] += ss[threadIdx.x + stp];
            sb[threadIdx.x] += sb[threadIdx.x + stp];
        }
        __syncthreads();
    }
    if (threadIdx.x == 0) {
        double mean = ss[0] / (double)N;
        double var = sb[0] / (double)N - mean * mean;
        float inv = gamma[c] / sqrtf((float)var + 1e-5f);
        float sh = rintf(log2f(fabsf(inv) + 1e-12f));
        sh = fminf(fmaxf(sh, -4.f), 4.f);
        float scale = copysignf(exp2f(sh), inv);
        st[c] = make_float4((float)mean, scale, beta[c], 0.f);
    }
}

// --- merged stats+finalize, int8 tensor [512][256][256] per channel ---
__global__ __launch_bounds__(1024) void k_statsfin8(const signed char* __restrict__ in,
                                                    const float* __restrict__ gamma,
                                                    const float* __restrict__ beta,
                                                    float4* __restrict__ st)
{
    int c = blockIdx.x;
    int s = 0, sq = 0;
    for (int i = threadIdx.x; i < 32768; i += 1024) {   // 512 b x 64 words
        int b = i >> 6, w = i & 63;
        u32 v = ((const u32*)in)[((size_t)(b * 256 + c) << 6) + w];
        int x0 = (int)(v << 24) >> 24, x1 = (int)(v << 16) >> 24;
        int x2 = (int)(v << 8) >> 24,  x3 = (int)v >> 24;
        s += x0 + x1 + x2 + x3;
        sq += x0 * x0 + x1 * x1 + x2 * x2 + x3 * x3;
    }
    __shared__ int ss[1024];
    __shared__ int sb[1024];
    ss[threadIdx.x] = s; sb[threadIdx.x] = sq;
    __syncthreads();
    for (int stp = 512; stp > 0; stp >>= 1) {
        if (threadIdx.x < stp) {
            ss[threadIdx.x] += ss[threadIdx.x + stp];
            sb[threadIdx.x] += sb[threadIdx.x + stp];
        }
        __syncthreads();
    }
    if (threadIdx.x == 0) {
        double mean = (double)ss[0] / 131072.0;
        double var = (double)sb[0] / 131072.0 - mean * mean;
        float inv = gamma[c] / sqrtf((float)var + 1e-5f);
        float sh = rintf(log2f(fabsf(inv) + 1e-12f));
        sh = fminf(fmaxf(sh, -4.f), 4.f);
        float scale = copysignf(exp2f(sh), inv);
        st[c] = make_float4((float)mean, scale, beta[c], 0.f);
    }
}

// --- merged stats+finalize, int16 tensor [512][256][64] per channel ---
__global__ __launch_bounds__(1024) void k_statsfin16(const short* __restrict__ in,
                                                     const float* __restrict__ gamma,
                                                     const float* __restrict__ beta,
                                                     float4* __restrict__ st)
{
    int c = blockIdx.x;
    int s = 0, sq = 0;
    for (int i = threadIdx.x; i < 16384; i += 1024) {   // 512 b x 32 words
        int b = i >> 5, w = i & 31;
        u32 v = ((const u32*)in)[((size_t)(b * 256 + c) << 5) + w];
        int x0 = (int)(v << 16) >> 16, x1 = (int)v >> 16;
        s += x0 + x1;
        sq += x0 * x0 + x1 * x1;
    }
    __shared__ double ss[1024];
    __shared__ double sb[1024];
    ss[threadIdx.x] = (double)s; sb[threadIdx.x] = (double)sq;
    __syncthreads();
    for (int stp = 512; stp > 0; stp >>= 1) {
        if (threadIdx.x < stp) {
            ss[threadIdx.x] += ss[threadIdx.x + stp];
            sb[threadIdx.x] += sb[threadIdx.x + stp];
        }
        __syncthreads();
    }
    if (threadIdx.x == 0) {
        double mean = ss[0] / 32768.0;
        double var = sb[0] / 32768.0 - mean * mean;
        float inv = gamma[c] / sqrtf((float)var + 1e-5f);
        float sh = rintf(log2f(fabsf(inv) + 1e-12f));
        sh = fminf(fmaxf(sh, -4.f), 4.f);
        float scale = copysignf(exp2f(sh), inv);
        st[c] = make_float4((float)mean, scale, beta[c], 0.f);
    }
}

// --- FUSED layer-2 head: block = (image, channel-half of 32). 256 thr. ---
__global__ __launch_bounds__(256) void k_fuse2(const float* __restrict__ ppool,
                                               const float4* __restrict__ st,
                                               const u32* __restrict__ wpk,
                                               signed char* __restrict__ out,
                                               double* __restrict__ part)
{
    __shared__ u32 lspk[32 * 20];
    __shared__ u32 lnpk[32 * 20];
    int b = blockIdx.x >> 1, half = blockIdx.x & 1;
    int t = threadIdx.x;
    // phase 1: bn + binarize + row-pack, 32 ch x 16 rows (2 items/thread)
#pragma unroll
    for (int k = 0; k < 2; ++k) {
        int e = t + k * 256;
        int cl = e >> 4, oh = e & 15;
        int c = half * 32 + cl;
        float4 s = st[c];
        const float4* p = (const float4*)(ppool + ((size_t)(b * 64 + c)) * 256 + oh * 16);
        u32 sb = 0, nb = 0;
#pragma unroll
        for (int j = 0; j < 4; ++j) {
            float4 v4 = p[j];
            float vs[4] = {v4.x, v4.y, v4.z, v4.w};
#pragma unroll
            for (int kk = 0; kk < 4; ++kk) {
                float v = (vs[kk] - s.x) * s.y + s.z;
                int ow = j * 4 + kk;
                sb |= (u32)(v > 0.f) << (ow + 1);
                nb |= (u32)(v != 0.f) << (ow + 1);
            }
        }
        lspk[cl * 20 + 1 + oh] = sb;
        lnpk[cl * 20 + 1 + oh] = nb;
        if (oh < 4) {
            int zs = (oh == 0) ? 0 : (16 + oh);
            lspk[cl * 20 + zs] = 0; lnpk[cl * 20 + zs] = 0;
        }
    }
    __syncthreads();
    // phase 2: grouped conv, 16 groups x 16 rows (1 item/thread)
    int gl = t >> 4, h = t & 15;
    int g = half * 16 + gl;
    const u32* sp = lspk + (2 * gl) * 20 + h;
    const u32* np = lnpk + (2 * gl) * 20 + h;
    u32 S[8], N[8];
#pragma unroll
    for (int jc = 0; jc < 2; ++jc)
#pragma unroll
        for (int jj = 0; jj < 4; ++jj) {
            S[jc * 4 + jj] = sp[jc * 20 + jj];
            N[jc * 4 + jj] = np[jc * 20 + jj];
        }
    const u32* wq = wpk + (size_t)(2 * g) * 8;
    u32 Ws0[8], Wn0[8], Ws1[8], Wn1[8];
#pragma unroll
    for (int r = 0; r < 8; ++r) {
        u32 a = wq[r];      Ws0[r] = a & 15u;  Wn0[r] = (a >> 8) & 15u;
        u32 bb = wq[8 + r]; Ws1[r] = bb & 15u; Wn1[r] = (bb >> 8) & 15u;
    }
    int v0[16], v1[16];
    int s0 = 0, q0 = 0, s1 = 0, q1 = 0;
#pragma unroll
    for (int w = 0; w < 16; ++w) {
        int snz0 = 0, smis0 = 0, snz1 = 0, smis1 = 0;
#pragma unroll
        for (int r = 0; r < 8; ++r) {
            u32 ss = (S[r] >> w) & 15u;
            u32 nn = (N[r] >> w) & 15u;
            u32 nz0 = nn & Wn0[r]; u32 m0 = (ss ^ Ws0[r]) & nz0;
            snz0 += __popc(nz0); smis0 += __popc(m0);
            u32 nz1 = nn & Wn1[r]; u32 m1 = (ss ^ Ws1[r]) & nz1;
            snz1 += __popc(nz1); smis1 += __popc(m1);
        }
        v0[w] = snz0 - 2 * smis0;
        v1[w] = snz1 - 2 * smis1;
        s0 += v0[w]; q0 += v0[w] * v0[w];
        s1 += v1[w]; q1 += v1[w] * v1[w];
    }
#pragma unroll
    for (int m = 1; m < 16; m <<= 1) {
        s0 += __shfl_xor(s0, m); q0 += __shfl_xor(q0, m);
        s1 += __shfl_xor(s1, m); q1 += __shfl_xor(q1, m);
    }
    if (h == 0) {
        part[((size_t)(2 * g) * 512 + b) * 2]         = (double)s0;
        part[((size_t)(2 * g) * 512 + b) * 2 + 1]     = (double)q0;
        part[((size_t)(2 * g + 1) * 512 + b) * 2]     = (double)s1;
        part[((size_t)(2 * g + 1) * 512 + b) * 2 + 1] = (double)q1;
    }
    signed char* o0 = out + ((size_t)((b * 64 + 2 * g) * 16 + h)) * 16;
    signed char* o1 = o0 + 256;
    u32 wb0[4], wb1[4];
#pragma unroll
    for (int j = 0; j < 4; ++j) {
        wb0[j] = pack4(v0[4*j], v0[4*j+1], v0[4*j+2], v0[4*j+3]);
        wb1[j] = pack4(v1[4*j], v1[4*j+1], v1[4*j+2], v1[4*j+3]);
    }
    *(uint4*)o0 = make_uint4(wb0[0], wb0[1], wb0[2], wb0[3]);
    *(uint4*)o1 = make_uint4(wb1[0], wb1[1], wb1[2], wb1[3]);
}

// --- 1x1 conv Cin=64->Cout=256 (oc halves), HW=256, FUSED bn binarize+pack ---
__global__ __launch_bounds__(256) void k_conv1x1_bp2(const signed char* __restrict__ q8,
                                                     const float4* __restrict__ st,
                                                     const u32* __restrict__ wp,
                                                     signed char* __restrict__ out)
{
    int b = blockIdx.x >> 1, hoc = blockIdx.x & 1;
    int hw = threadIdx.x;
    const signed char* qp = q8 + (size_t)b * 64 * 256 + hw;
    u32 as0 = 0, as1 = 0, an0 = 0, an1 = 0;
#pragma unroll
    for (int k = 0; k < 32; ++k) {
        float4 s = st[k];                       // uniform -> s_load
        float v = ((float)qp[k * 256] - s.x) * s.y + s.z;   // coalesced byte load
        as0 |= (u32)(v > 0.f) << k;
        an0 |= (u32)(v != 0.f) << k;
    }
#pragma unroll
    for (int k = 0; k < 32; ++k) {
        float4 s = st[32 + k];
        float v = ((float)qp[(32 + k) * 256] - s.x) * s.y + s.z;
        as1 |= (u32)(v > 0.f) << k;
        an1 |= (u32)(v != 0.f) << k;
    }
    signed char* op = out + (size_t)b * 256 * 256 + hw;
    int oc0 = hoc * 128;
#pragma unroll 8
    for (int oc = oc0; oc < oc0 + 128; ++oc) {
        uint4 wv = ((const uint4*)wp)[oc];      // wave-uniform -> scalar loads
        u32 nz0 = an0 & wv.z, nz1 = an1 & wv.w;
        u32 m0 = (as0 ^ wv.x) & nz0, m1 = (as1 ^ wv.y) & nz1;
        int dot = __popc(nz0) + __popc(nz1) - 2 * (__popc(m0) + __popc(m1));
        op[(size_t)oc << 8] = (signed char)dot;
    }
}

// --- FUSED layer-3 head: block = (image, quarter of 64 ch / 32 groups). ---
__global__ __launch_bounds__(256) void k_fuse3(const signed char* __restrict__ c22,
                                               const float4* __restrict__ st,
                                               const u32* __restrict__ wpk,
                                               signed char* __restrict__ out,
                                               double* __restrict__ part)
{
    __shared__ u32 lspk[64 * 12];
    __shared__ u32 lnpk[64 * 12];
    int b = blockIdx.x >> 2, qd = blockIdx.x & 3;
    int t = threadIdx.x;
    // phase 1: bn+pool+binarize+pack, 64 ch x 8 rows (2 items/thread)
#pragma unroll
    for (int k = 0; k < 2; ++k) {
        int e = t + k * 256;
        int cl = e >> 3, oh = e & 7;
        int c = qd * 64 + cl;
        float4 s = st[c];
        const uint4* p = (const uint4*)(c22 + ((size_t)(b * 256 + c)) * 256 + (size_t)(2 * oh) * 16);
        uint4 r0 = p[0], r1 = p[1];
        bool pos = (s.y > 0.f);
        u32 rows0[4] = {r0.x, r0.y, r0.z, r0.w};
        u32 rows1[4] = {r1.x, r1.y, r1.z, r1.w};
        u32 sb = 0, nb = 0;
#pragma unroll
        for (int j = 0; j < 4; ++j) {
            u32 a = rows0[j], bw = rows1[j];
#pragma unroll
            for (int kk = 0; kk < 2; ++kk) {
                int sh0 = 24 - 16 * kk, sh1 = 16 - 16 * kk;
                int a0 = (int)(a  << sh0) >> 24, a1 = (int)(a  << sh1) >> 24;
                int a2 = (int)(bw << sh0) >> 24, a3 = (int)(bw << sh1) >> 24;
                int raw = pos ? max(max(a0, a1), max(a2, a3))
                              : min(min(a0, a1), min(a2, a3));
                float v = ((float)raw - s.x) * s.y + s.z;
                int ow = j * 2 + kk;
                sb |= (u32)(v > 0.f) << (ow + 1);
                nb |= (u32)(v != 0.f) << (ow + 1);
            }
        }
        lspk[cl * 12 + 1 + oh] = sb;
        lnpk[cl * 12 + 1 + oh] = nb;
        if (oh < 4) {
            int zs = (oh == 0) ? 0 : (8 + oh);
            lspk[cl * 12 + zs] = 0; lnpk[cl * 12 + zs] = 0;
        }
    }
    __syncthreads();
    // phase 2: grouped conv, 32 groups x 8 rows (1 item/thread)
    int gl = t >> 3, h = t & 7;
    int g = qd * 32 + gl;
    const u32* sp = lspk + (2 * gl) * 12 + h;
    const u32* np = lnpk + (2 * gl) * 12 + h;
    u32 S[8], N[8];
#pragma unroll
    for (int jc = 0; jc < 2; ++jc)
#pragma unroll
        for (int jj = 0; jj < 4; ++jj) {
            S[jc * 4 + jj] = sp[jc * 12 + jj];
            N[jc * 4 + jj] = np[jc * 12 + jj];
        }
    const u32* wq = wpk + (size_t)(2 * g) * 8;
    u32 Ws0[8], Wn0[8], Ws1[8], Wn1[8];
#pragma unroll
    for (int r = 0; r < 8; ++r) {
        u32 a = wq[r];      Ws0[r] = a & 15u;  Wn0[r] = (a >> 8) & 15u;
        u32 bb = wq[8 + r]; Ws1[r] = bb & 15u; Wn1[r] = (bb >> 8) & 15u;
    }
    int v0[8], v1[8];
    int s0 = 0, q0 = 0, s1 = 0, q1 = 0;
#pragma unroll
    for (int w = 0; w < 8; ++w) {
        int snz0 = 0, smis0 = 0, snz1 = 0, smis1 = 0;
#pragma unroll
        for (int r = 0; r < 8; ++r) {
            u32 ss = (S[r] >> w) & 15u;
            u32 nn = (N[r] >> w) & 15u;
            u32 nz0 = nn & Wn0[r]; u32 m0 = (ss ^ Ws0[r]) & nz0;
            snz0 += __popc(nz0); smis0 += __popc(m0);
            u32 nz1 = nn & Wn1[r]; u32 m1 = (ss ^ Ws1[r]) & nz1;
            snz1 += __popc(nz1); smis1 += __popc(m1);
        }
        v0[w] = snz0 - 2 * smis0;
        v1[w] = snz1 - 2 * smis1;
        s0 += v0[w]; q0 += v0[w] * v0[w];
        s1 += v1[w]; q1 += v1[w] * v1[w];
    }
#pragma unroll
    for (int m = 1; m < 8; m <<= 1) {
        s0 += __shfl_xor(s0, m); q0 += __shfl_xor(q0, m);
        s1 += __shfl_xor(s1, m); q1 += __shfl_xor(q1, m);
    }
    if (h == 0) {
        part[((size_t)(2 * g) * 512 + b) * 2]         = (double)s0;
        part[((size_t)(2 * g) * 512 + b) * 2 + 1]     = (double)q0;
        part[((size_t)(2 * g + 1) * 512 + b) * 2]     = (double)s1;
        part[((size_t)(2 * g + 1) * 512 + b) * 2 + 1] = (double)q1;
    }
    signed char* o0 = out + ((size_t)((b * 256 + 2 * g) * 8 + h)) * 8;
    signed char* o1 = o0 + 64;
    *(uint2*)o0 = make_uint2(pack4(v0[0], v0[1], v0[2], v0[3]),
                             pack4(v0[4], v0[5], v0[6], v0[7]));
    *(uint2*)o1 = make_uint2(pack4(v1[0], v1[1], v1[2], v1[3]),
                             pack4(v1[4], v1[5], v1[6], v1[7]));
}

// --- FUSED: bn+binarize+channel-pack (LDS) -> 1x1 conv Cin=256, int16 out ---
__global__ __launch_bounds__(256) void k_fuse4(const signed char* __restrict__ q8,
                                               const float4* __restrict__ st,
                                               const u32* __restrict__ wp,
                                               short* __restrict__ out)
{
    __shared__ u32 sq[4096];       // one image: 256ch x 64hw bytes
    __shared__ u32 act[64 * 17];   // [hw][16 words], pad 17
    int b = blockIdx.x, t = threadIdx.x;
    const u32* qb = (const u32*)(q8 + (size_t)b * 16384);
    for (int i = t; i < 4096; i += 256) sq[i] = qb[i];
    __syncthreads();
    {
        const signed char* s8p = (const signed char*)sq;
        int hw = t & 63, qd = t >> 6;
        u32 sv0 = 0, nv0 = 0, sv1 = 0, nv1 = 0;
#pragma unroll
        for (int k = 0; k < 32; ++k) {
            int c = qd * 64 + k;
            float4 s = st[c];
            float v = ((float)s8p[c * 64 + hw] - s.x) * s.y + s.z;
            sv0 |= (u32)(v > 0.f) << k;
            nv0 |= (u32)(v != 0.f) << k;
        }
#pragma unroll
        for (int k = 0; k < 32; ++k) {
            int c = qd * 64 + 32 + k;
            float4 s = st[c];
            float v = ((float)s8p[c * 64 + hw] - s.x) * s.y + s.z;
            sv1 |= (u32)(v > 0.f) << k;
            nv1 |= (u32)(v != 0.f) << k;
        }
        u32* ap = act + hw * 17;
        ap[qd * 2]     = sv0;
        ap[qd * 2 + 1] = sv1;
        ap[8 + qd * 2]     = nv0;
        ap[8 + qd * 2 + 1] = nv1;
    }
    __syncthreads();
    int hw = t & 63, ch = t >> 6;
    const u32* ap = act + hw * 17;
    u32 as[8], an[8];
#pragma unroll
    for (int j = 0; j < 8; ++j) { as[j] = ap[j]; an[j] = ap[8 + j]; }
    short* op = out + (size_t)b * 256 * 64 + hw;
#pragma unroll 4
    for (int oc = ch * 64; oc < ch * 64 + 64; ++oc) {
        const u32* wq = wp + oc * 16;
        int snz = 0, smis = 0;
#pragma unroll
        for (int j = 0; j < 8; ++j) {
            u32 nz = an[j] & wq[8 + j];
            u32 m = (as[j] ^ wq[j]) & nz;
            snz += __popc(nz); smis += __popc(m);
        }
        op[(size_t)oc * 64] = (short)(snz - 2 * smis);
    }
}

// --- FC: block = 2 images (512 thr), bn3_2 inline, fcw reused x2 ---
__global__ __launch_bounds__(512) void k_fc2(const short* __restrict__ f,
                                             const float4* __restrict__ st,
                                             const float* __restrict__ fcw,
                                             const float* __restrict__ fcb,
                                             float* __restrict__ out)
{
    int b0 = blockIdx.x * 2, t = threadIdx.x;
    int lane = t & 63, wv = t >> 6;
    const u32* fpA = (const u32*)(f + (size_t)b0 * 16384);
    const u32* fpB = (const u32*)(f + (size_t)(b0 + 1) * 16384);
    float accA[10], accB[10];
#pragma unroll
    for (int n = 0; n < 10; ++n) { accA[n] = 0.f; accB[n] = 0.f; }
    for (int i = 0; i < 16; ++i) {
        int j = i * 512 + t;                 // u32 index; features 2j, 2j+1
        u32 vA = fpA[j];
        u32 vB = fpB[j];
        float4 s = st[j >> 5];               // channel = (2j)>>6 = j>>5
        float fA0 = ((float)((int)(vA << 16) >> 16) - s.x) * s.y + s.z;
        float fA1 = ((float)((int)vA >> 16) - s.x) * s.y + s.z;
        float fB0 = ((float)((int)(vB << 16) >> 16) - s.x) * s.y + s.z;
        float fB1 = ((float)((int)vB >> 16) - s.x) * s.y + s.z;
#pragma unroll
        for (int n = 0; n < 10; ++n) {
            float2 wv2 = *(const float2*)(fcw + (size_t)n * 16384 + 2 * j);
            accA[n] = __builtin_fmaf(fA0, wv2.x, accA[n]);
            accA[n] = __builtin_fmaf(fA1, wv2.y, accA[n]);
            accB[n] = __builtin_fmaf(fB0, wv2.x, accB[n]);
            accB[n] = __builtin_fmaf(fB1, wv2.y, accB[n]);
        }
    }
#pragma unroll
    for (int n = 0; n < 10; ++n)
#pragma unroll
        for (int m = 1; m < 64; m <<= 1) {
            accA[n] += __shfl_xor(accA[n], m);
            accB[n] += __shfl_xor(accB[n], m);
        }
    __shared__ float sredA[8][10];
    __shared__ float sredB[8][10];
    if (lane == 0)
#pragma unroll
        for (int n = 0; n < 10; ++n) { sredA[wv][n] = accA[n]; sredB[wv][n] = accB[n]; }
    __syncthreads();
    if (t < 10) {
        float r = fcb[t];
#pragma unroll
        for (int w = 0; w < 8; ++w) r += sredA[w][t];
        out[b0 * 10 + t] = r;
    } else if (t >= 64 && t < 74) {
        int n = t - 64;
        float r = fcb[n];
#pragma unroll
        for (int w = 0; w < 8; ++w) r += sredB[w][n];
        out[(b0 + 1) * 10 + n] = r;
    }
}

extern "C" void kernel_launch(void* const* d_in, const int* in_sizes, int n_in,
                              void* d_out, int out_size, void* d_ws, size_t ws_size,
                              hipStream_t stream)
{
    const float* x    = (const float*)d_in[0];
    const float* w1   = (const float*)d_in[1];
    const float* g1   = (const float*)d_in[2];
    const float* b1   = (const float*)d_in[3];
    const float* w2_1 = (const float*)d_in[4];
    const float* g2_1 = (const float*)d_in[5];
    const float* b2_1 = (const float*)d_in[6];
    const float* w2_2 = (const float*)d_in[7];
    const float* g2_2 = (const float*)d_in[8];
    const float* b2_2 = (const float*)d_in[9];
    const float* w3_1 = (const float*)d_in[10];
    const float* g3_1 = (const float*)d_in[11];
    const float* b3_1 = (const float*)d_in[12];
    const float* w3_2 = (const float*)d_in[13];
    const float* g3_2 = (const float*)d_in[14];
    const float* b3_2 = (const float*)d_in[15];
    const float* fcw  = (const float*)d_in[16];
    const float* fcb  = (const float*)d_in[17];
    float* out = (float*)d_out;

    // workspace layout (bytes). ppool aliases later c22 (write-after-consume
    // ordering per launch sequence).
    const size_t OFF_PPOOL= 0;          // 33,554,432  (-> c22 later)
    const size_t OFF_F3   = 33554432;   // 16,777,216  conv3_2 int16 out
    const size_t OFF_Q    = 50331648;   //  8,388,608  convg int8 outs
    const size_t OFF_WPK21= 67108864;   //  2,048
    const size_t OFF_WPK31= 67110912;   //  8,192
    const size_t OFF_WP22 = 67119104;   //  4,096
    const size_t OFF_WP32 = 67123200;   //  16,384
    const size_t OFF_PART = 67139584;   //  2,097,152
    const size_t OFF_ST   = 69236736;   //  20,480     5 x 256 float4
    const size_t OFF_SWT  = 69257216;   //  12,288     conv1 signed weights, tap-major f32
    const size_t OFF_XPAD = 69269504;   //  7,741,440  padded input [512*3][35][36]
    const size_t NEED     = OFF_XPAD + 7741440;
    if (ws_size < NEED) return;

    char* ws = (char*)d_ws;
    float* ppool = (float*)(ws + OFF_PPOOL);
    signed char* c22 = (signed char*)(ws + OFF_PPOOL); // after k_fuse2 consumes ppool
    short* f3  = (short*)(ws + OFF_F3);
    signed char* q8 = (signed char*)(ws + OFF_Q);
    u32* wpk21 = (u32*)(ws + OFF_WPK21);
    u32* wpk31 = (u32*)(ws + OFF_WPK31);
    u32* wp22  = (u32*)(ws + OFF_WP22);
    u32* wp32  = (u32*)(ws + OFF_WP32);
    double* part = (double*)(ws + OFF_PART);
    float4* st1  = (float4*)(ws + OFF_ST);
    float4* st21 = st1 + 256;
    float4* st22 = st21 + 256;
    float4* st31 = st22 + 256;
    float4* st32 = st31 + 256;
    float* swt   = (float*)(ws + OFF_SWT);
    float* xpad  = (float*)(ws + OFF_XPAD);

    // ---- weight prep + input pad (one launch) ----
    k_wprep<<<7574, 256, 0, stream>>>(w1, swt, w2_1, wpk21, w3_1, wpk31,
                                      w2_2, wp22, w3_2, wp32, x, xpad);

    // ---- layer 1 ----
    k_conv1f<<<4096, 256, 0, stream>>>(xpad, swt, g1, ppool, part);
    k_finalize2<<<64, 256, 0, stream>>>(part, 512, 512 * 1024, g1, b1, st1);

    // ---- layer 2 (pack+gconv fused, channel-split) ----
    k_fuse2<<<1024, 256, 0, stream>>>(ppool, st1, wpk21, q8, part);
    k_finalize2<<<64, 256, 0, stream>>>(part, 512, 512 * 256, g2_1, b2_1, st21);
    k_conv1x1_bp2<<<1024, 256, 0, stream>>>(q8, st21, wp22, c22);
    k_statsfin8<<<256, 1024, 0, stream>>>(c22, g2_2, b2_2, st22);

    // ---- layer 3 (pool+pack+gconv fused, quarter-split; pack+1x1 fused) ----
    k_fuse3<<<2048, 256, 0, stream>>>(c22, st22, wpk31, q8, part);
    k_finalize2<<<256, 256, 0, stream>>>(part, 512, 512 * 64, g3_1, b3_1, st31);
    k_fuse4<<<512, 256, 0, stream>>>(q8, st31, wp32, f3);
    k_statsfin16<<<256, 1024, 0, stream>>>(f3, g3_2, b3_2, st32);

    // ---- FC (bn3_2 inline, 2 images/block) ----
    k_fc2<<<256, 512, 0, stream>>>(f3, st32, fcw, fcb, out);
}